// Round 7
// baseline (1414.718 us; speedup 1.0000x reference)
//
#include <hip/hip_runtime.h>
#include <hip/hip_bf16.h>
#include <stdint.h>

#define N 100000
#define E_ 1600000
#define D 128
#define C_ 256
#define HID 64
#define KSEL 80000
#define NB 4096
#define CHUNK 1024
#define NCHUNK ((N + CHUNK - 1) / CHUNK)   // 98
#define CSEG 32                            // segments per cluster for mean reduction
#define NBK 782                            // ceil(N/128) dst-buckets of 128 nodes
#define BCAP 2560                          // per-bucket capacity (avg 2046 + >11 sigma)
#define RMAX 2048                          // LDS key capacity for in-bucket ranking
#define NSC64 ((N + 63) / 64)              // 1563 score blocks
#define EB ((E_ + 255) / 256)              // 6250 edge blocks
#define ZB ((N * 32 + 255) / 256)          // 12500 zero-row blocks

typedef __attribute__((ext_vector_type(8))) short bf16x8;
typedef __attribute__((ext_vector_type(4))) float f32x4;

// ---- ordered-float encoding (monotonic increasing uint) ----
__device__ __forceinline__ unsigned enc_f(float f) {
  unsigned b = __float_as_uint(f);
  return (b & 0x80000000u) ? ~b : (b | 0x80000000u);
}
__device__ __forceinline__ float dec_f(unsigned u) {
  unsigned b = (u & 0x80000000u) ? (u ^ 0x80000000u) : ~u;
  return __uint_as_float(b);
}

// fp32 -> bf16 round-to-nearest-even (finite inputs)
__device__ __forceinline__ unsigned short f2bf(float f) {
  unsigned u = __float_as_uint(f);
  unsigned r = u + 0x7FFFu + ((u >> 16) & 1u);
  return (unsigned short)(r >> 16);
}

// ======================= cluster CSR + means =======================
__global__ __launch_bounds__(256) void k_hist_cluster(const int* __restrict__ cid, int* __restrict__ ccount) {
  int n = blockIdx.x * 256 + threadIdx.x;
  if (n < N) atomicAdd(&ccount[cid[n]], 1);
}

// generic small scan; block b scans in[b*n .. b*n+n) -> out exclusive
__global__ __launch_bounds__(1024) void k_scan_small(const int* __restrict__ in0, int* __restrict__ out0, int n) {
  __shared__ int sums[1024];
  const int* in = in0 + (size_t)blockIdx.x * n;
  int* out = out0 + (size_t)blockIdx.x * n;
  int t = threadIdx.x;
  int per = (n + 1023) / 1024;
  int base = t * per;
  int loc = 0;
  for (int k = 0; k < per; ++k) { int i = base + k; if (i < n) loc += in[i]; }
  sums[t] = loc; __syncthreads();
  for (int off = 1; off < 1024; off <<= 1) {
    int v = (t >= off) ? sums[t - off] : 0;
    __syncthreads();
    sums[t] += v;
    __syncthreads();
  }
  int run = (t == 0) ? 0 : sums[t - 1];
  for (int k = 0; k < per; ++k) { int i = base + k; if (i < n) { out[i] = run; run += in[i]; } }
}

__global__ __launch_bounds__(256) void k_scatter_cluster(const int* __restrict__ cid, const int* __restrict__ cstart,
                                                         int* __restrict__ ccur, int* __restrict__ cslot) {
  int n = blockIdx.x * 256 + threadIdx.x;
  if (n < N) {
    int c = cid[n];
    int p = cstart[c] + atomicAdd(&ccur[c], 1);
    cslot[p] = n;
  }
}

__global__ __launch_bounds__(128) void k_cluster_partial(const float* __restrict__ x, const int* __restrict__ cstart,
                                                         const int* __restrict__ ccount, const int* __restrict__ cslot,
                                                         float* __restrict__ Hc) {
  int c = blockIdx.x >> 5;
  int s = blockIdx.x & (CSEG - 1);
  int d = threadIdx.x;
  int st = cstart[c], cnt = ccount[c];
  int seg = (cnt + CSEG - 1) / CSEG;
  int lo = s * seg;
  int hi = min(cnt, lo + seg);
  if (lo >= hi) return;
  float acc = 0.f;
  int k = lo;
  for (; k + 2 <= hi; k += 2) {
    int n0 = cslot[st + k], n1 = cslot[st + k + 1];
    float v0 = x[(size_t)n0 * D + d];
    float v1 = x[(size_t)n1 * D + d];
    acc += v0 + v1;
  }
  if (k < hi) acc += x[(size_t)cslot[st + k] * D + d];
  atomicAdd(&Hc[(size_t)c * D + d], acc);
}

// divide Hc by counts, then gdot[c] = Hc[c] . wb  (merged, one launch)
__global__ __launch_bounds__(128) void k_mean_gdot(const int* __restrict__ ccount, const float* __restrict__ wb,
                                                   float* __restrict__ Hc, float* __restrict__ gdot) {
  __shared__ float red[128];
  int c = blockIdx.x, d = threadIdx.x;
  float hv = Hc[(size_t)c * D + d] / (float)max(ccount[c], 1);
  Hc[(size_t)c * D + d] = hv;
  red[d] = hv * wb[d];
  __syncthreads();
  if (d < 64) {
    float v = red[d] + red[d + 64];
    for (int off = 32; off; off >>= 1) v += __shfl_down(v, off);
    if (d == 0) gdot[c] = v;
  }
}

// block 0: S = sum_c Hc[c], SW = S @ tw ; blocks 1..C_: HW[b-1] = Hc[b-1] @ tw ;
// blocks C_+1 .. C_+D: twT row (b-C_-1) = bf16 transpose of tw (folded k_twT).
__global__ __launch_bounds__(128) void k_S_SW_HW(const float* __restrict__ Hc, const float* __restrict__ tw,
                                                 float* __restrict__ SW, float* __restrict__ HW,
                                                 unsigned short* __restrict__ twT) {
  __shared__ float Sl[128];
  int b = blockIdx.x, t = threadIdx.x;
  if (b == 0) {
    float s = 0.f;
    for (int c = 0; c < C_; ++c) s += Hc[(size_t)c * D + t];
    Sl[t] = s;
    __syncthreads();
    float acc = 0.f;
    for (int d = 0; d < D; ++d) acc = fmaf(Sl[d], tw[(size_t)d * D + t], acc);
    SW[t] = acc;
  } else if (b <= C_) {
    const float* src = Hc + (size_t)(b - 1) * D;
    float acc = 0.f;
    for (int d = 0; d < D; ++d) acc = fmaf(src[d], tw[(size_t)d * D + t], acc);
    HW[(size_t)(b - 1) * D + t] = acc;
  } else {
    int k = b - C_ - 1;   // 0..127 ; twT[o][k] = bf16(tw[k][o]), o = t (coalesced read)
    twT[(size_t)t * D + k] = f2bf(tw[(size_t)k * D + t]);
  }
}

// ======== fused per-node scores: MLP (feature view) + GAT h/aDot ========
// fp32 throughout (scoreF drives an exact top-K selection). Round-6 loop body
// (proven) widened to 512 threads over the SAME 64-row/32KB tile: 2 rows x 4
// cols per thread. Per-output summation order unchanged -> scoreF/hg/aDot
// bit-identical to round 6. Thread-cap now allows 4 blocks/CU = 32 waves/CU
// (vs ~10 observed at 256 threads) to hide the LDS/VMEM latency chains.
// launch_bounds(512,8) caps VGPR at 64 (round-6 build used 44) so occupancy
// is LDS/thread-limited, not register-limited.
__global__ __launch_bounds__(512, 8) void k_score64(const float* __restrict__ x, const float* __restrict__ w1,
                                                    const float* __restrict__ b1, const float* __restrict__ w2,
                                                    const float* __restrict__ b2, const float* __restrict__ gw,
                                                    const float* __restrict__ wa, float* __restrict__ scoreF,
                                                    float* __restrict__ hg, float* __restrict__ aDot,
                                                    uint2* __restrict__ pmmF) {
  __shared__ float xld[64 * D];  // 32 KB, swizzled by float4 chunk
  int tid = threadIdx.x;
  int base = blockIdx.x * 64;
#pragma unroll
  for (int k = 0; k < 4; ++k) {
    int i = k * 512 + tid;
    int r = i >> 5, cc = i & 31;
    int n = base + r;
    float4 v = make_float4(0.f, 0.f, 0.f, 0.f);
    if (n < N) v = ((const float4*)(x + (size_t)n * D))[cc];
    ((float4*)xld)[r * 32 + (cc ^ (r & 7))] = v;
  }
  __syncthreads();

  int rg = tid >> 4;        // 32 row-groups of 2 rows
  int cg = tid & 15;        // 16 col-groups of 4 hid cols
  int r0 = rg * 2;
  int c4 = cg * 4;
  float acc[2][4] = {};
  float4 wc0 = *(const float4*)(w1 + (size_t)0 * HID + c4);
  float4 wc1 = *(const float4*)(w1 + (size_t)1 * HID + c4);
  float4 wc2 = *(const float4*)(w1 + (size_t)2 * HID + c4);
  float4 wc3 = *(const float4*)(w1 + (size_t)3 * HID + c4);
  for (int d4 = 0; d4 < D; d4 += 4) {
    float4 wn0, wn1, wn2, wn3;
    if (d4 + 4 < D) {  // prefetch next w1 slab; used only after the FMA block
      wn0 = *(const float4*)(w1 + (size_t)(d4 + 4) * HID + c4);
      wn1 = *(const float4*)(w1 + (size_t)(d4 + 5) * HID + c4);
      wn2 = *(const float4*)(w1 + (size_t)(d4 + 6) * HID + c4);
      wn3 = *(const float4*)(w1 + (size_t)(d4 + 7) * HID + c4);
    } else {
      wn0 = wn1 = wn2 = wn3 = make_float4(0.f, 0.f, 0.f, 0.f);
    }
    int j = d4 >> 2;
#pragma unroll
    for (int rr = 0; rr < 2; ++rr) {
      int row = r0 + rr;
      float4 xv = ((const float4*)xld)[row * 32 + (j ^ (row & 7))];
      acc[rr][0] = fmaf(xv.x, wc0.x, acc[rr][0]);
      acc[rr][1] = fmaf(xv.x, wc0.y, acc[rr][1]);
      acc[rr][2] = fmaf(xv.x, wc0.z, acc[rr][2]);
      acc[rr][3] = fmaf(xv.x, wc0.w, acc[rr][3]);
      acc[rr][0] = fmaf(xv.y, wc1.x, acc[rr][0]);
      acc[rr][1] = fmaf(xv.y, wc1.y, acc[rr][1]);
      acc[rr][2] = fmaf(xv.y, wc1.z, acc[rr][2]);
      acc[rr][3] = fmaf(xv.y, wc1.w, acc[rr][3]);
      acc[rr][0] = fmaf(xv.z, wc2.x, acc[rr][0]);
      acc[rr][1] = fmaf(xv.z, wc2.y, acc[rr][1]);
      acc[rr][2] = fmaf(xv.z, wc2.z, acc[rr][2]);
      acc[rr][3] = fmaf(xv.z, wc2.w, acc[rr][3]);
      acc[rr][0] = fmaf(xv.w, wc3.x, acc[rr][0]);
      acc[rr][1] = fmaf(xv.w, wc3.y, acc[rr][1]);
      acc[rr][2] = fmaf(xv.w, wc3.z, acc[rr][2]);
      acc[rr][3] = fmaf(xv.w, wc3.w, acc[rr][3]);
    }
    wc0 = wn0; wc1 = wn1; wc2 = wn2; wc3 = wn3;
  }

  float4 b1v = *(const float4*)(b1 + c4);
  float4 w2v = *(const float4*)(w2 + c4);
  float bb = b2[0];
  unsigned vmx = 0u, vmn = 0xFFFFFFFFu;
#pragma unroll
  for (int rr = 0; rr < 2; ++rr) {
    float p = fmaxf(acc[rr][0] + b1v.x, 0.f) * w2v.x
            + fmaxf(acc[rr][1] + b1v.y, 0.f) * w2v.y
            + fmaxf(acc[rr][2] + b1v.z, 0.f) * w2v.z
            + fmaxf(acc[rr][3] + b1v.w, 0.f) * w2v.w;
#pragma unroll
    for (int off = 8; off; off >>= 1) p += __shfl_xor(p, off);  // 16-lane group reduce
    if (cg == 0) {
      int n = base + r0 + rr;
      if (n < N) {
        float sf = p + bb;
        scoreF[n] = sf;
        unsigned e = enc_f(sf);
        vmx = max(vmx, e);
        vmn = min(vmn, e);
      }
    }
  }
  // wave-level scoreF min/max (register-only; block combine at the end)
#pragma unroll
  for (int off = 32; off; off >>= 1) {
    vmx = max(vmx, (unsigned)__shfl_xor((int)vmx, off));
    vmn = min(vmn, (unsigned)__shfl_xor((int)vmn, off));
  }

  float4 gwa = *(const float4*)(gw + c4);
  float4 gwb = *(const float4*)(gw + 64 + c4);
  float4 waa = *(const float4*)(wa + c4);
  float4 wab = *(const float4*)(wa + 64 + c4);
#pragma unroll
  for (int rr = 0; rr < 2; ++rr) {
    int row = r0 + rr;
    float4 xa = ((const float4*)xld)[row * 32 + (cg ^ (row & 7))];
    float4 xb = ((const float4*)xld)[row * 32 + ((cg + 16) ^ (row & 7))];
    float hp = xa.x * gwa.x + xa.y * gwa.y + xa.z * gwa.z + xa.w * gwa.w
             + xb.x * gwb.x + xb.y * gwb.y + xb.z * gwb.z + xb.w * gwb.w;
    float ap = xa.x * waa.x + xa.y * waa.y + xa.z * waa.z + xa.w * waa.w
             + xb.x * wab.x + xb.y * wab.y + xb.z * wab.z + xb.w * wab.w;
#pragma unroll
    for (int off = 8; off; off >>= 1) {
      hp += __shfl_xor(hp, off);
      ap += __shfl_xor(ap, off);
    }
    if (cg == 0) {
      int n = base + row;
      if (n < N) { hg[n] = hp; aDot[n] = ap; }
    }
  }

  // block combine through (now-dead) xld; one plain store, no atomics
  __syncthreads();
  if ((tid & 63) == 0) {
    ((unsigned*)xld)[(tid >> 6) * 2] = vmx;
    ((unsigned*)xld)[(tid >> 6) * 2 + 1] = vmn;
  }
  __syncthreads();
  if (tid == 0) {
    const unsigned* xu = (const unsigned*)xld;
    unsigned a = 0u, b = 0xFFFFFFFFu;
#pragma unroll
    for (int w = 0; w < 8; ++w) {
      a = max(a, xu[w * 2]);
      b = min(b, xu[w * 2 + 1]);
    }
    pmmF[blockIdx.x] = make_uint2(a, b);
  }
}

// Bucket edges by dst>>7 with LDS-aggregated reservation. Payload is 4 B/edge
// (s | dl<<24); the GAT logit is recomputed bit-identically in k_esoftmax.
__global__ __launch_bounds__(1024) void k_escatter(const int* __restrict__ ei, int* __restrict__ gcnt,
                                                   unsigned* __restrict__ payload) {
  __shared__ int lcnt[NBK];
  __shared__ int lbase[NBK];
  int tid = threadIdx.x;
  for (int i = tid; i < NBK; i += 1024) lcnt[i] = 0;
  int e0 = blockIdx.x * 8192;
  int es[8], ed[8];
#pragma unroll
  for (int k = 0; k < 8; ++k) {
    int e = e0 + k * 1024 + tid;
    bool v = (e < E_);
    es[k] = v ? ei[e] : -1;
    ed[k] = v ? ei[E_ + e] : -1;
  }
  __syncthreads();
#pragma unroll
  for (int k = 0; k < 8; ++k)
    if (ed[k] >= 0) atomicAdd(&lcnt[ed[k] >> 7], 1);
  __syncthreads();
  for (int i = tid; i < NBK; i += 1024) {
    int c = lcnt[i];
    lbase[i] = c ? atomicAdd(&gcnt[i], c) : 0;
    lcnt[i] = 0;
  }
  __syncthreads();
#pragma unroll
  for (int k = 0; k < 8; ++k) {
    if (ed[k] < 0) continue;
    int s = es[k], d = ed[k];
    int b = d >> 7, dl = d & 127;
    int pos = lbase[b] + atomicAdd(&lcnt[b], 1);
    if (pos < BCAP) payload[(size_t)b * BCAP + pos] = (unsigned)s | ((unsigned)dl << 24);
  }
}

// Per-bucket GAT softmax in LDS; recomputes the logit from hg (hg[dst] staged
// in LDS, hg[src] from L2) and writes scoreL + per-block min/max partial
// (plain store; no contended atomics).
__global__ __launch_bounds__(256) void k_esoftmax(const unsigned* __restrict__ payload, const int* __restrict__ gcnt,
                                                  const float* __restrict__ hg, const float* __restrict__ asrc,
                                                  const float* __restrict__ adst, const float* __restrict__ gb,
                                                  float* __restrict__ scoreL, uint2* __restrict__ pmmL) {
  __shared__ unsigned mS[128];
  __shared__ float dS[128];
  __shared__ float nS[128];
  __shared__ float hgl[128];
  __shared__ unsigned pw[8];
  int b = blockIdx.x;
  int tid = threadIdx.x;
  if (tid < 128) {
    mS[tid] = 0u; dS[tid] = 0.f; nS[tid] = 0.f;
    int g = b * 128 + tid;
    hgl[tid] = (g < N) ? hg[g] : 0.f;
  }
  __syncthreads();
  float as = asrc[0], ad = adst[0];
  int cnt = min(gcnt[b], BCAP);
  const unsigned* bp = payload + (size_t)b * BCAP;
  for (int i = tid; i < cnt; i += 256) {
    unsigned r = bp[i];
    int s = (int)(r & 0xFFFFFFu), dl = (int)(r >> 24);
    float z = as * hg[s] + ad * hgl[dl];
    float ev = (z > 0.f) ? z : 0.2f * z;
    atomicMax(&mS[dl], enc_f(ev));
  }
  __syncthreads();
  for (int i = tid; i < cnt; i += 256) {
    unsigned r = bp[i];
    int s = (int)(r & 0xFFFFFFu), dl = (int)(r >> 24);
    float h = hg[s];
    float z = as * h + ad * hgl[dl];
    float ev = (z > 0.f) ? z : 0.2f * z;
    float ex = expf(ev - dec_f(mS[dl]));
    atomicAdd(&dS[dl], ex);
    atomicAdd(&nS[dl], ex * h);
  }
  __syncthreads();
  unsigned vmx = 0u, vmn = 0xFFFFFFFFu;
  if (tid < 128) {
    int dst = b * 128 + tid;
    if (dst < N) {
      float sl = nS[tid] / fmaxf(dS[tid], 1e-16f) + gb[0];
      scoreL[dst] = sl;
      unsigned e = enc_f(sl);
      vmx = e; vmn = e;
    }
  }
#pragma unroll
  for (int off = 32; off; off >>= 1) {
    vmx = max(vmx, (unsigned)__shfl_xor((int)vmx, off));
    vmn = min(vmn, (unsigned)__shfl_xor((int)vmn, off));
  }
  if ((tid & 63) == 0) { pw[(tid >> 6) * 2] = vmx; pw[(tid >> 6) * 2 + 1] = vmn; }
  __syncthreads();
  if (tid == 0) {
    unsigned a = max(max(pw[0], pw[2]), max(pw[4], pw[6]));
    unsigned c = min(min(pw[1], pw[3]), min(pw[5], pw[7]));
    pmmL[b] = make_uint2(a, c);
  }
}

// single-block reduce of per-block minmax partials -> mm[maxF,maxL,minF,minL]
__global__ __launch_bounds__(1024) void k_mm_reduce(const uint2* __restrict__ pmmF, const uint2* __restrict__ pmmL,
                                                    unsigned* __restrict__ mm) {
  __shared__ unsigned s[4][16];
  int t = threadIdx.x;
  unsigned mxF = 0u, mnF = 0xFFFFFFFFu, mxL = 0u, mnL = 0xFFFFFFFFu;
  for (int i = t; i < NSC64; i += 1024) {
    uint2 v = pmmF[i];
    mxF = max(mxF, v.x); mnF = min(mnF, v.y);
  }
  for (int i = t; i < NBK; i += 1024) {
    uint2 v = pmmL[i];
    mxL = max(mxL, v.x); mnL = min(mnL, v.y);
  }
#pragma unroll
  for (int off = 32; off; off >>= 1) {
    mxF = max(mxF, (unsigned)__shfl_xor((int)mxF, off));
    mnF = min(mnF, (unsigned)__shfl_xor((int)mnF, off));
    mxL = max(mxL, (unsigned)__shfl_xor((int)mxL, off));
    mnL = min(mnL, (unsigned)__shfl_xor((int)mnL, off));
  }
  int w = t >> 6;
  if ((t & 63) == 0) { s[0][w] = mxF; s[1][w] = mnF; s[2][w] = mxL; s[3][w] = mnL; }
  __syncthreads();
  if (t == 0) {
    unsigned a = 0u, b = 0xFFFFFFFFu, c = 0u, d = 0xFFFFFFFFu;
    for (int i = 0; i < 16; ++i) {
      a = max(a, s[0][i]); b = min(b, s[1][i]);
      c = max(c, s[2][i]); d = min(d, s[3][i]);
    }
    mm[0] = a; mm[2] = b; mm[1] = c; mm[3] = d;
  }
}

// ========== exact top-k ranking, both views per launch (blockIdx.y) ==========
__global__ __launch_bounds__(256) void k_bucket_hist2(const float* __restrict__ sc2, const unsigned* __restrict__ mm,
                                                      int* __restrict__ bucket2, int* __restrict__ hist2) {
  int v = blockIdx.y;
  int n = blockIdx.x * 256 + threadIdx.x;
  if (n >= N) return;
  const float* sc = sc2 + (size_t)v * N;
  float smax = dec_f(mm[v]), smin = dec_f(mm[2 + v]);
  float range = smax - smin;
  float scale = (range > 0.f) ? ((float)NB / range) : 0.f;
  float t = (smax - sc[n]) * scale;
  int b = (int)t;
  b = b < 0 ? 0 : (b > NB - 1 ? NB - 1 : b);
  bucket2[(size_t)v * N + n] = b;
  atomicAdd(&hist2[v * NB + b], 1);
}

__global__ __launch_bounds__(256) void k_bucket_scatter2(const int* __restrict__ bucket2, const int* __restrict__ start2,
                                                         int* __restrict__ cur2, int* __restrict__ slot2) {
  int v = blockIdx.y;
  int n = blockIdx.x * 256 + threadIdx.x;
  if (n >= N) return;
  int b = bucket2[(size_t)v * N + n];
  slot2[(size_t)v * N + start2[v * NB + b] + atomicAdd(&cur2[v * NB + b], 1)] = n;
}

// Bucket-centric exact ranking: one wave per bucket, keys staged in LDS once.
__global__ __launch_bounds__(64) void k_bucket_rank3(const float* __restrict__ sc2, const int* __restrict__ start2,
                                                     const int* __restrict__ hist2, const int* __restrict__ slot2,
                                                     int* __restrict__ rank2, int* __restrict__ sorted2) {
  __shared__ unsigned long long keys[RMAX];
  int v = blockIdx.y;
  int b = blockIdx.x;
  int st = start2[v * NB + b], cnt = hist2[v * NB + b];
  if (cnt == 0) return;
  const float* sc = sc2 + (size_t)v * N;
  const int* slot = slot2 + (size_t)v * N;
  int* rank = rank2 + (size_t)v * N;
  int* sorted = sorted2 + (size_t)v * N;
  int tid = threadIdx.x;
  if (cnt <= RMAX) {
    for (int i = tid; i < cnt; i += 64) {
      int m = slot[st + i];
      keys[i] = (((unsigned long long)(~enc_f(sc[m]))) << 32) | (unsigned)m;
    }
    __syncthreads();
    for (int i = tid; i < cnt; i += 64) {
      unsigned long long mykey = keys[i];
      int r = 0;
      for (int j = 0; j < cnt; ++j) r += (keys[j] < mykey) ? 1 : 0;
      int m = (int)(mykey & 0xFFFFFFFFu);
      rank[m] = st + r;
      sorted[st + r] = m;
    }
  } else {  // degenerate-distribution fallback
    for (int i = tid; i < cnt; i += 64) {
      int m = slot[st + i];
      unsigned long long mykey = (((unsigned long long)(~enc_f(sc[m]))) << 32) | (unsigned)m;
      int r = 0;
      for (int j = 0; j < cnt; ++j) {
        int mj = slot[st + j];
        unsigned long long k = (((unsigned long long)(~enc_f(sc[mj]))) << 32) | (unsigned)mj;
        r += (k < mykey) ? 1 : 0;
      }
      rank[m] = st + r;
      sorted[st + r] = m;
    }
  }
}

// ======================= union mapping =======================
__global__ __launch_bounds__(1024) void k_union_chunksum(const int* __restrict__ rankF, const int* __restrict__ rankL,
                                                         int* __restrict__ csum) {
  __shared__ int red[1024];
  int t = threadIdx.x; int i = blockIdx.x * 1024 + t;
  int u = (i < N) ? (((rankF[i] < KSEL) || (rankL[i] < KSEL)) ? 1 : 0) : 0;
  red[t] = u; __syncthreads();
  for (int off = 512; off; off >>= 1) { if (t < off) red[t] += red[t + off]; __syncthreads(); }
  if (t == 0) csum[blockIdx.x] = red[0];
}

__global__ __launch_bounds__(1024) void k_union_map(const int* __restrict__ rankF, const int* __restrict__ rankL,
                                                    const int* __restrict__ cstart, const int* __restrict__ batch,
                                                    int* __restrict__ mapping, float* __restrict__ outBatch) {
  __shared__ int sums[1024];
  int t = threadIdx.x; int i = blockIdx.x * 1024 + t;
  int u = (i < N) ? (((rankF[i] < KSEL) || (rankL[i] < KSEL)) ? 1 : 0) : 0;
  sums[t] = u; __syncthreads();
  for (int off = 1; off < 1024; off <<= 1) {
    int v = (t >= off) ? sums[t - off] : 0;
    __syncthreads();
    sums[t] += v;
    __syncthreads();
  }
  if (i < N) {
    mapping[i] = u ? (cstart[blockIdx.x] + sums[t] - 1) : -1;
    outBatch[i] = u ? (float)batch[i] : -1.0f;
  }
}

// merged: edge remap (blocks [0,EB)) + zero non-union Fp rows (blocks [EB,EB+ZB))
__global__ __launch_bounds__(256) void k_edge_zero(const int* __restrict__ ei, const int* __restrict__ mapping,
                                                   float* __restrict__ outE, float* __restrict__ Fp) {
  int b = blockIdx.x;
  if (b < EB) {
    int e = b * 256 + threadIdx.x;
    if (e >= E_) return;
    int m0 = mapping[ei[e]], m1 = mapping[ei[E_ + e]];
    bool valid = (m0 >= 0) && (m1 >= 0);
    outE[e] = valid ? (float)m0 : -1.f;
    outE[E_ + e] = valid ? (float)m1 : -1.f;
  } else {
    int i = (b - EB) * 256 + threadIdx.x;  // over N*32 float4s
    int n = i >> 5;
    if (n < N && mapping[n] < 0) ((float4*)Fp)[i] = make_float4(0.f, 0.f, 0.f, 0.f);
  }
}

// ======================= fused GCN transform + scatter (MFMA) =======================
// Fp[tgtL[i]] (+)= relu( x[srcL[i]] @ tw + tb + q*SW + (p-q)*HW[cid[srcL[i]]] )
// bf16 MFMA version: compute out^T tiles via D = twT(16o x 32k) . xT(32k x 16n)
// with mfma_f32_16x16x32_bf16. C/D layout (m89-verified): col=lane&15 -> node,
// row=(lane>>4)*4+reg -> 4 consecutive out-channels => coalesced float4 stores.
// x staged in LDS as bf16 [64][128] with XOR swizzle byte^=((row&7)<<4) to break
// the 16-way bank conflict on the stride-256B ds_read_b128 B-frag reads (T2).
// All 4 B-frags preloaded before the MFMA chain (ds_read latency off the
// critical path); twT (bf16, pre-transposed) read straight from global (L1/L2).
__global__ __launch_bounds__(256, 4) void k_fuse64(const float* __restrict__ x, const unsigned short* __restrict__ twT,
                                                   const float* __restrict__ tb, const float* __restrict__ SW,
                                                   const float* __restrict__ HW, const float* __restrict__ gdot,
                                                   const float* __restrict__ aDot, const int* __restrict__ cid,
                                                   const int* __restrict__ srcL, const int* __restrict__ tgtL,
                                                   const float* __restrict__ attb, const int* __restrict__ rankF,
                                                   float* __restrict__ Fp, int accum) {
  __shared__ __align__(16) unsigned xw[64 * 64];  // 64 rows x 128 bf16 cols, 16 KB, swizzled
  __shared__ float pq[64 * 2];
  __shared__ int mt[64 * 2];
  __shared__ int ft[64];
  int tid = threadIdx.x;
  int base = blockIdx.x * 64;
  if (tid < 64) {
    int ws = srcL[base + tid];
    int cc = cid[ws];
    int tg = tgtL[base + tid];
    mt[tid * 2] = cc;
    mt[tid * 2 + 1] = tg;
    ft[tid] = (rankF[tg] < KSEL) ? 1 : 0;
    float s = aDot[ws] + gdot[cc] + attb[0];
    float mx = fmaxf(s, 0.f);
    float esm = expf(s - mx), eom = expf(-mx);
    float dn = esm + 255.f * eom;
    pq[tid * 2] = esm / dn;
    pq[tid * 2 + 1] = eom / dn;
  }
  // stage 64 x-rows as bf16 (2048 float4 loads -> 2048 uint2 LDS writes)
#pragma unroll
  for (int k = 0; k < 8; ++k) {
    int i = k * 256 + tid;
    int r = i >> 5, c4 = i & 31;
    int ws = srcL[base + r];
    float4 v = ((const float4*)(x + (size_t)ws * D))[c4];
    uint2 pk;
    pk.x = (unsigned)f2bf(v.x) | ((unsigned)f2bf(v.y) << 16);
    pk.y = (unsigned)f2bf(v.z) | ((unsigned)f2bf(v.w) << 16);
    int u2 = r * 32 + (c4 ^ ((r & 7) << 1));  // byte = r*256 + ((c4*8) ^ ((r&7)<<4))
    ((uint2*)xw)[u2] = pk;
  }
  __syncthreads();

  int w = tid >> 6;        // wave 0..3 -> node rows w*16 .. w*16+15
  int l = tid & 63;
  int nl = l & 15;         // node within tile (D col)
  int khalf = l >> 4;      // k-block / out-ch subrow selector
  int row = w * 16 + nl;   // LDS x row this lane's B-frags come from

  f32x4 acc[8] = {};       // 8 out-ch tiles of 16 (full 128 out-channels)
  const char* xbase = (const char*)xw + row * 256;
  unsigned rsw = (unsigned)((row & 7) << 4);
  bf16x8 bfr[4];
#pragma unroll
  for (int ks = 0; ks < 4; ++ks)
    bfr[ks] = *(const bf16x8*)(xbase + (((unsigned)(ks * 64 + khalf * 16)) ^ rsw));
#pragma unroll
  for (int ks = 0; ks < 4; ++ks) {
#pragma unroll
    for (int ot = 0; ot < 8; ++ot) {
      // A-frag: twT[ot*16 + nl][ks*32 + khalf*8 .. +7] (16 B from L1/L2)
      bf16x8 afrag = *(const bf16x8*)(twT + (size_t)(ot * 16 + nl) * D + ks * 32 + khalf * 8);
      acc[ot] = __builtin_amdgcn_mfma_f32_16x16x32_bf16(afrag, bfr[ks], acc[ot], 0, 0, 0);
    }
  }

  // epilogue: lane owns node (w*16+nl), channels ot*16 + khalf*4 .. +3
  float p = pq[row * 2], q = pq[row * 2 + 1];
  int cc = mt[row * 2];
  int tgt = mt[row * 2 + 1];
  int doAcc = accum && ft[row];
#pragma unroll
  for (int ot = 0; ot < 8; ++ot) {
    int ch = ot * 16 + khalf * 4;
    float4 tbv = *(const float4*)(tb + ch);
    float4 swv = *(const float4*)(SW + ch);
    float4 hw = *(const float4*)(HW + (size_t)cc * D + ch);
    float4 o;
    o.x = fmaxf(acc[ot][0] + tbv.x + q * swv.x + (p - q) * hw.x, 0.f);
    o.y = fmaxf(acc[ot][1] + tbv.y + q * swv.y + (p - q) * hw.y, 0.f);
    o.z = fmaxf(acc[ot][2] + tbv.z + q * swv.z + (p - q) * hw.z, 0.f);
    o.w = fmaxf(acc[ot][3] + tbv.w + q * swv.w + (p - q) * hw.w, 0.f);
    float4* dst = (float4*)(Fp + (size_t)tgt * D + ch);
    if (doAcc) {
      float4 old = *dst;
      o.x = (o.x + old.x) * 0.5f;
      o.y = (o.y + old.y) * 0.5f;
      o.z = (o.z + old.z) * 0.5f;
      o.w = (o.w + old.w) * 0.5f;
    }
    *dst = o;
  }
}

// ======================= launcher =======================
extern "C" void kernel_launch(void* const* d_in, const int* in_sizes, int n_in,
                              void* d_out, int out_size, void* d_ws, size_t ws_size,
                              hipStream_t stream) {
  const float* x   = (const float*)d_in[0];
  const int* ei    = (const int*)d_in[1];
  const int* batch = (const int*)d_in[2];
  const int* cid   = (const int*)d_in[3];
  const float* w1  = (const float*)d_in[4];
  const float* b1  = (const float*)d_in[5];
  const float* w2  = (const float*)d_in[6];
  const float* b2  = (const float*)d_in[7];
  const float* gw  = (const float*)d_in[8];
  const float* gas = (const float*)d_in[9];
  const float* gad = (const float*)d_in[10];
  const float* gb  = (const float*)d_in[11];
  const float* wa  = (const float*)d_in[12];
  const float* wb  = (const float*)d_in[13];
  const float* ab  = (const float*)d_in[14];
  const float* tw  = (const float*)d_in[15];
  const float* tb  = (const float*)d_in[16];
  (void)in_sizes; (void)n_in; (void)ws_size; (void)out_size;

  char* p = (char*)d_ws;
  auto alloc = [&](size_t bytes) -> char* {
    char* r = p;
    p += (bytes + 255) & ~(size_t)255;
    return r;
  };
  // ---- zero-init region ----
  int* ccount    = (int*)alloc(C_ * 4);
  int* ccur      = (int*)alloc(C_ * 4);
  unsigned* mm   = (unsigned*)alloc(16);                // [maxF,maxL,minF,minL]
  int* hist2     = (int*)alloc(2 * NB * 4);
  int* cur2      = (int*)alloc(2 * NB * 4);
  float* Hc      = (float*)alloc((size_t)C_ * D * 4);   // atomic accumulator
  int* gcnt      = (int*)alloc(NBK * 4);
  size_t zeroBytes = (size_t)(p - (char*)d_ws);
  // ---- rest (fully written before read) ----
  int* cstart   = (int*)alloc(C_ * 4);
  int* cslot    = (int*)alloc((size_t)N * 4);
  float* gdot   = (float*)alloc(C_ * 4);
  float* SW     = (float*)alloc(D * 4);
  float* HW     = (float*)alloc((size_t)C_ * D * 4);
  unsigned short* twT = (unsigned short*)alloc((size_t)D * D * 2);
  float* score2 = (float*)alloc((size_t)2 * N * 4);     // [scoreF | scoreL]
  float* hg     = (float*)alloc((size_t)N * 4);
  float* aDot   = (float*)alloc((size_t)N * 4);
  unsigned* payload = (unsigned*)alloc((size_t)NBK * BCAP * 4);
  uint2* pmmF   = (uint2*)alloc((size_t)NSC64 * 8);
  uint2* pmmL   = (uint2*)alloc((size_t)NBK * 8);
  int* bucket2  = (int*)alloc((size_t)2 * N * 4);
  int* start2   = (int*)alloc(2 * NB * 4);
  int* slot2    = (int*)alloc((size_t)2 * N * 4);
  int* sorted2  = (int*)alloc((size_t)2 * N * 4);
  int* rank2    = (int*)alloc((size_t)2 * N * 4);
  int* csums    = (int*)alloc(NCHUNK * 4);
  int* cstarts  = (int*)alloc(NCHUNK * 4);
  int* mapping  = (int*)alloc((size_t)N * 4);

  float* scoreF = score2;
  float* scoreL = score2 + N;
  int* sortedF  = sorted2;
  int* sortedL  = sorted2 + N;
  int* rankF    = rank2;
  int* rankL    = rank2 + N;

  float* outF = (float*)d_out;             // [N, D]
  float* outE = outF + (size_t)N * D;      // [2, E]  (fully written by k_edge_zero)
  float* outB = outE + (size_t)2 * E_;     // [N]     (fully written by k_union_map)

  hipMemsetAsync(d_ws, 0, zeroBytes, stream);
  // outF: union rows fully written by the two fuse launches (store / cond-accum);
  // non-union rows zeroed by k_edge_zero -> no 51 MB memset.

  // cluster means + derived (+ twT transpose folded into k_S_SW_HW grid)
  k_hist_cluster<<<(N + 255) / 256, 256, 0, stream>>>(cid, ccount);
  k_scan_small<<<1, 1024, 0, stream>>>(ccount, cstart, C_);
  k_scatter_cluster<<<(N + 255) / 256, 256, 0, stream>>>(cid, cstart, ccur, cslot);
  k_cluster_partial<<<C_ * CSEG, 128, 0, stream>>>(x, cstart, ccount, cslot, Hc);
  k_mean_gdot<<<C_, 128, 0, stream>>>(ccount, wb, Hc, gdot);
  k_S_SW_HW<<<C_ + 1 + D, 128, 0, stream>>>(Hc, tw, SW, HW, twT);

  // fused per-node scores (MLP + GAT projections + minmax partials) + edge softmax
  k_score64<<<NSC64, 512, 0, stream>>>(x, w1, b1, w2, b2, gw, wa, scoreF, hg, aDot, pmmF);
  k_escatter<<<(E_ + 8191) / 8192, 1024, 0, stream>>>(ei, gcnt, payload);
  k_esoftmax<<<NBK, 256, 0, stream>>>(payload, gcnt, hg, gas, gad, gb, scoreL, pmmL);
  k_mm_reduce<<<1, 1024, 0, stream>>>(pmmF, pmmL, mm);

  // exact ranking, both views per launch (minmax folded into producers + 1-block reduce)
  dim3 g2((N + 255) / 256, 2);
  k_bucket_hist2<<<g2, 256, 0, stream>>>(score2, mm, bucket2, hist2);
  k_scan_small<<<2, 1024, 0, stream>>>(hist2, start2, NB);
  k_bucket_scatter2<<<g2, 256, 0, stream>>>(bucket2, start2, cur2, slot2);
  dim3 gr(NB, 2);
  k_bucket_rank3<<<gr, 64, 0, stream>>>(score2, start2, hist2, slot2, rank2, sorted2);

  // union mapping + edge remap + batch + zero non-union rows (merged)
  k_union_chunksum<<<NCHUNK, 1024, 0, stream>>>(rankF, rankL, csums);
  k_scan_small<<<1, 1024, 0, stream>>>(csums, cstarts, NCHUNK);
  k_union_map<<<NCHUNK, 1024, 0, stream>>>(rankF, rankL, cstarts, batch, mapping, outB);
  k_edge_zero<<<EB + ZB, 256, 0, stream>>>(ei, mapping, outE, outF);

  // fused features: launch 1 pure-stores (feat rows); launch 2 stores or
  // accumulates+halves (local rows) depending on feat membership.
  k_fuse64<<<KSEL / 64, 256, 0, stream>>>(x, twT, tb, SW, HW, gdot, aDot, cid, sortedL, sortedF, ab, rankF, outF, 0);
  k_fuse64<<<KSEL / 64, 256, 0, stream>>>(x, twT, tb, SW, HW, gdot, aDot, cid, sortedF, sortedL, ab, rankF, outF, 1);
}

// Round 8
// 1303.294 us; speedup vs baseline: 1.0855x; 1.0855x over previous
//
#include <hip/hip_runtime.h>
#include <hip/hip_bf16.h>
#include <stdint.h>

#define N 100000
#define E_ 1600000
#define D 128
#define C_ 256
#define HID 64
#define KSEL 80000
#define NB 4096
#define CHUNK 1024
#define NCHUNK ((N + CHUNK - 1) / CHUNK)   // 98
#define CSEG 32                            // segments per cluster for mean reduction
#define NBK 782                            // ceil(N/128) dst-buckets of 128 nodes
#define BCAP 2560                          // per-bucket capacity (avg 2046 + >11 sigma)
#define RMAX 2048                          // LDS key capacity for in-bucket ranking
#define NSC64 ((N + 63) / 64)              // 1563 score blocks
#define EB ((E_ + 255) / 256)              // 6250 edge blocks
#define ZB ((N * 32 + 255) / 256)          // 12500 zero-row blocks

typedef __attribute__((ext_vector_type(8))) short bf16x8;
typedef __attribute__((ext_vector_type(4))) float f32x4;

// ---- ordered-float encoding (monotonic increasing uint) ----
__device__ __forceinline__ unsigned enc_f(float f) {
  unsigned b = __float_as_uint(f);
  return (b & 0x80000000u) ? ~b : (b | 0x80000000u);
}
__device__ __forceinline__ float dec_f(unsigned u) {
  unsigned b = (u & 0x80000000u) ? (u ^ 0x80000000u) : ~u;
  return __uint_as_float(b);
}

// fp32 -> bf16 round-to-nearest-even (finite inputs)
__device__ __forceinline__ unsigned short f2bf(float f) {
  unsigned u = __float_as_uint(f);
  unsigned r = u + 0x7FFFu + ((u >> 16) & 1u);
  return (unsigned short)(r >> 16);
}

// ======================= cluster CSR + means =======================
__global__ __launch_bounds__(256) void k_hist_cluster(const int* __restrict__ cid, int* __restrict__ ccount) {
  int n = blockIdx.x * 256 + threadIdx.x;
  if (n < N) atomicAdd(&ccount[cid[n]], 1);
}

// generic small scan; block b scans in[b*n .. b*n+n) -> out exclusive
__global__ __launch_bounds__(1024) void k_scan_small(const int* __restrict__ in0, int* __restrict__ out0, int n) {
  __shared__ int sums[1024];
  const int* in = in0 + (size_t)blockIdx.x * n;
  int* out = out0 + (size_t)blockIdx.x * n;
  int t = threadIdx.x;
  int per = (n + 1023) / 1024;
  int base = t * per;
  int loc = 0;
  for (int k = 0; k < per; ++k) { int i = base + k; if (i < n) loc += in[i]; }
  sums[t] = loc; __syncthreads();
  for (int off = 1; off < 1024; off <<= 1) {
    int v = (t >= off) ? sums[t - off] : 0;
    __syncthreads();
    sums[t] += v;
    __syncthreads();
  }
  int run = (t == 0) ? 0 : sums[t - 1];
  for (int k = 0; k < per; ++k) { int i = base + k; if (i < n) { out[i] = run; run += in[i]; } }
}

__global__ __launch_bounds__(256) void k_scatter_cluster(const int* __restrict__ cid, const int* __restrict__ cstart,
                                                         int* __restrict__ ccur, int* __restrict__ cslot) {
  int n = blockIdx.x * 256 + threadIdx.x;
  if (n < N) {
    int c = cid[n];
    int p = cstart[c] + atomicAdd(&ccur[c], 1);
    cslot[p] = n;
  }
}

__global__ __launch_bounds__(128) void k_cluster_partial(const float* __restrict__ x, const int* __restrict__ cstart,
                                                         const int* __restrict__ ccount, const int* __restrict__ cslot,
                                                         float* __restrict__ Hc) {
  int c = blockIdx.x >> 5;
  int s = blockIdx.x & (CSEG - 1);
  int d = threadIdx.x;
  int st = cstart[c], cnt = ccount[c];
  int seg = (cnt + CSEG - 1) / CSEG;
  int lo = s * seg;
  int hi = min(cnt, lo + seg);
  if (lo >= hi) return;
  float acc = 0.f;
  int k = lo;
  for (; k + 2 <= hi; k += 2) {
    int n0 = cslot[st + k], n1 = cslot[st + k + 1];
    float v0 = x[(size_t)n0 * D + d];
    float v1 = x[(size_t)n1 * D + d];
    acc += v0 + v1;
  }
  if (k < hi) acc += x[(size_t)cslot[st + k] * D + d];
  atomicAdd(&Hc[(size_t)c * D + d], acc);
}

// divide Hc by counts, then gdot[c] = Hc[c] . wb  (merged, one launch)
__global__ __launch_bounds__(128) void k_mean_gdot(const int* __restrict__ ccount, const float* __restrict__ wb,
                                                   float* __restrict__ Hc, float* __restrict__ gdot) {
  __shared__ float red[128];
  int c = blockIdx.x, d = threadIdx.x;
  float hv = Hc[(size_t)c * D + d] / (float)max(ccount[c], 1);
  Hc[(size_t)c * D + d] = hv;
  red[d] = hv * wb[d];
  __syncthreads();
  if (d < 64) {
    float v = red[d] + red[d + 64];
    for (int off = 32; off; off >>= 1) v += __shfl_down(v, off);
    if (d == 0) gdot[c] = v;
  }
}

// block 0: S = sum_c Hc[c], SW = S @ tw ; blocks 1..C_: HW[b-1] = Hc[b-1] @ tw ;
// blocks C_+1 .. C_+D: twT row (b-C_-1) = bf16 transpose of tw (folded k_twT).
__global__ __launch_bounds__(128) void k_S_SW_HW(const float* __restrict__ Hc, const float* __restrict__ tw,
                                                 float* __restrict__ SW, float* __restrict__ HW,
                                                 unsigned short* __restrict__ twT) {
  __shared__ float Sl[128];
  int b = blockIdx.x, t = threadIdx.x;
  if (b == 0) {
    float s = 0.f;
    for (int c = 0; c < C_; ++c) s += Hc[(size_t)c * D + t];
    Sl[t] = s;
    __syncthreads();
    float acc = 0.f;
    for (int d = 0; d < D; ++d) acc = fmaf(Sl[d], tw[(size_t)d * D + t], acc);
    SW[t] = acc;
  } else if (b <= C_) {
    const float* src = Hc + (size_t)(b - 1) * D;
    float acc = 0.f;
    for (int d = 0; d < D; ++d) acc = fmaf(src[d], tw[(size_t)d * D + t], acc);
    HW[(size_t)(b - 1) * D + t] = acc;
  } else {
    int k = b - C_ - 1;   // 0..127 ; twT[o][k] = bf16(tw[k][o]), o = t (coalesced read)
    twT[(size_t)t * D + k] = f2bf(tw[(size_t)k * D + t]);
  }
}

// ======== fused per-node scores: MLP (feature view) + GAT h/aDot ========
// fp32 throughout (scoreF drives an exact top-K selection). Round-6 loop body
// widened to 512 threads over the SAME 64-row/32KB tile: 2 rows x 4 cols per
// thread; per-output summation order unchanged -> outputs bit-identical.
// launch_bounds(512, 4): min 4 waves/EU -> VGPR budget 128 >> ~40 needed.
// ROUND-7 LESSON: (512, 8) forced VGPR<=~32 -> 3 GB/dispatch scratch spill
// traffic, 17x slowdown. The 2nd arg is a VGPR cap in disguise.
__global__ __launch_bounds__(512, 4) void k_score64(const float* __restrict__ x, const float* __restrict__ w1,
                                                    const float* __restrict__ b1, const float* __restrict__ w2,
                                                    const float* __restrict__ b2, const float* __restrict__ gw,
                                                    const float* __restrict__ wa, float* __restrict__ scoreF,
                                                    float* __restrict__ hg, float* __restrict__ aDot,
                                                    uint2* __restrict__ pmmF) {
  __shared__ float xld[64 * D];  // 32 KB, swizzled by float4 chunk
  int tid = threadIdx.x;
  int base = blockIdx.x * 64;
#pragma unroll
  for (int k = 0; k < 4; ++k) {
    int i = k * 512 + tid;
    int r = i >> 5, cc = i & 31;
    int n = base + r;
    float4 v = make_float4(0.f, 0.f, 0.f, 0.f);
    if (n < N) v = ((const float4*)(x + (size_t)n * D))[cc];
    ((float4*)xld)[r * 32 + (cc ^ (r & 7))] = v;
  }
  __syncthreads();

  int rg = tid >> 4;        // 32 row-groups of 2 rows
  int cg = tid & 15;        // 16 col-groups of 4 hid cols
  int r0 = rg * 2;
  int c4 = cg * 4;
  float acc[2][4] = {};
  float4 wc0 = *(const float4*)(w1 + (size_t)0 * HID + c4);
  float4 wc1 = *(const float4*)(w1 + (size_t)1 * HID + c4);
  float4 wc2 = *(const float4*)(w1 + (size_t)2 * HID + c4);
  float4 wc3 = *(const float4*)(w1 + (size_t)3 * HID + c4);
  for (int d4 = 0; d4 < D; d4 += 4) {
    float4 wn0, wn1, wn2, wn3;
    if (d4 + 4 < D) {  // prefetch next w1 slab; used only after the FMA block
      wn0 = *(const float4*)(w1 + (size_t)(d4 + 4) * HID + c4);
      wn1 = *(const float4*)(w1 + (size_t)(d4 + 5) * HID + c4);
      wn2 = *(const float4*)(w1 + (size_t)(d4 + 6) * HID + c4);
      wn3 = *(const float4*)(w1 + (size_t)(d4 + 7) * HID + c4);
    } else {
      wn0 = wn1 = wn2 = wn3 = make_float4(0.f, 0.f, 0.f, 0.f);
    }
    int j = d4 >> 2;
#pragma unroll
    for (int rr = 0; rr < 2; ++rr) {
      int row = r0 + rr;
      float4 xv = ((const float4*)xld)[row * 32 + (j ^ (row & 7))];
      acc[rr][0] = fmaf(xv.x, wc0.x, acc[rr][0]);
      acc[rr][1] = fmaf(xv.x, wc0.y, acc[rr][1]);
      acc[rr][2] = fmaf(xv.x, wc0.z, acc[rr][2]);
      acc[rr][3] = fmaf(xv.x, wc0.w, acc[rr][3]);
      acc[rr][0] = fmaf(xv.y, wc1.x, acc[rr][0]);
      acc[rr][1] = fmaf(xv.y, wc1.y, acc[rr][1]);
      acc[rr][2] = fmaf(xv.y, wc1.z, acc[rr][2]);
      acc[rr][3] = fmaf(xv.y, wc1.w, acc[rr][3]);
      acc[rr][0] = fmaf(xv.z, wc2.x, acc[rr][0]);
      acc[rr][1] = fmaf(xv.z, wc2.y, acc[rr][1]);
      acc[rr][2] = fmaf(xv.z, wc2.z, acc[rr][2]);
      acc[rr][3] = fmaf(xv.z, wc2.w, acc[rr][3]);
      acc[rr][0] = fmaf(xv.w, wc3.x, acc[rr][0]);
      acc[rr][1] = fmaf(xv.w, wc3.y, acc[rr][1]);
      acc[rr][2] = fmaf(xv.w, wc3.z, acc[rr][2]);
      acc[rr][3] = fmaf(xv.w, wc3.w, acc[rr][3]);
    }
    wc0 = wn0; wc1 = wn1; wc2 = wn2; wc3 = wn3;
  }

  float4 b1v = *(const float4*)(b1 + c4);
  float4 w2v = *(const float4*)(w2 + c4);
  float bb = b2[0];
  unsigned vmx = 0u, vmn = 0xFFFFFFFFu;
#pragma unroll
  for (int rr = 0; rr < 2; ++rr) {
    float p = fmaxf(acc[rr][0] + b1v.x, 0.f) * w2v.x
            + fmaxf(acc[rr][1] + b1v.y, 0.f) * w2v.y
            + fmaxf(acc[rr][2] + b1v.z, 0.f) * w2v.z
            + fmaxf(acc[rr][3] + b1v.w, 0.f) * w2v.w;
#pragma unroll
    for (int off = 8; off; off >>= 1) p += __shfl_xor(p, off);  // 16-lane group reduce
    if (cg == 0) {
      int n = base + r0 + rr;
      if (n < N) {
        float sf = p + bb;
        scoreF[n] = sf;
        unsigned e = enc_f(sf);
        vmx = max(vmx, e);
        vmn = min(vmn, e);
      }
    }
  }
  // wave-level scoreF min/max (register-only; block combine at the end)
#pragma unroll
  for (int off = 32; off; off >>= 1) {
    vmx = max(vmx, (unsigned)__shfl_xor((int)vmx, off));
    vmn = min(vmn, (unsigned)__shfl_xor((int)vmn, off));
  }

  float4 gwa = *(const float4*)(gw + c4);
  float4 gwb = *(const float4*)(gw + 64 + c4);
  float4 waa = *(const float4*)(wa + c4);
  float4 wab = *(const float4*)(wa + 64 + c4);
#pragma unroll
  for (int rr = 0; rr < 2; ++rr) {
    int row = r0 + rr;
    float4 xa = ((const float4*)xld)[row * 32 + (cg ^ (row & 7))];
    float4 xb = ((const float4*)xld)[row * 32 + ((cg + 16) ^ (row & 7))];
    float hp = xa.x * gwa.x + xa.y * gwa.y + xa.z * gwa.z + xa.w * gwa.w
             + xb.x * gwb.x + xb.y * gwb.y + xb.z * gwb.z + xb.w * gwb.w;
    float ap = xa.x * waa.x + xa.y * waa.y + xa.z * waa.z + xa.w * waa.w
             + xb.x * wab.x + xb.y * wab.y + xb.z * wab.z + xb.w * wab.w;
#pragma unroll
    for (int off = 8; off; off >>= 1) {
      hp += __shfl_xor(hp, off);
      ap += __shfl_xor(ap, off);
    }
    if (cg == 0) {
      int n = base + row;
      if (n < N) { hg[n] = hp; aDot[n] = ap; }
    }
  }

  // block combine through (now-dead) xld; one plain store, no atomics
  __syncthreads();
  if ((tid & 63) == 0) {
    ((unsigned*)xld)[(tid >> 6) * 2] = vmx;
    ((unsigned*)xld)[(tid >> 6) * 2 + 1] = vmn;
  }
  __syncthreads();
  if (tid == 0) {
    const unsigned* xu = (const unsigned*)xld;
    unsigned a = 0u, b = 0xFFFFFFFFu;
#pragma unroll
    for (int w = 0; w < 8; ++w) {
      a = max(a, xu[w * 2]);
      b = min(b, xu[w * 2 + 1]);
    }
    pmmF[blockIdx.x] = make_uint2(a, b);
  }
}

// Bucket edges by dst>>7 with LDS-aggregated reservation. Payload is 4 B/edge
// (s | dl<<24); the GAT logit is recomputed bit-identically in k_esoftmax.
__global__ __launch_bounds__(1024) void k_escatter(const int* __restrict__ ei, int* __restrict__ gcnt,
                                                   unsigned* __restrict__ payload) {
  __shared__ int lcnt[NBK];
  __shared__ int lbase[NBK];
  int tid = threadIdx.x;
  for (int i = tid; i < NBK; i += 1024) lcnt[i] = 0;
  int e0 = blockIdx.x * 8192;
  int es[8], ed[8];
#pragma unroll
  for (int k = 0; k < 8; ++k) {
    int e = e0 + k * 1024 + tid;
    bool v = (e < E_);
    es[k] = v ? ei[e] : -1;
    ed[k] = v ? ei[E_ + e] : -1;
  }
  __syncthreads();
#pragma unroll
  for (int k = 0; k < 8; ++k)
    if (ed[k] >= 0) atomicAdd(&lcnt[ed[k] >> 7], 1);
  __syncthreads();
  for (int i = tid; i < NBK; i += 1024) {
    int c = lcnt[i];
    lbase[i] = c ? atomicAdd(&gcnt[i], c) : 0;
    lcnt[i] = 0;
  }
  __syncthreads();
#pragma unroll
  for (int k = 0; k < 8; ++k) {
    if (ed[k] < 0) continue;
    int s = es[k], d = ed[k];
    int b = d >> 7, dl = d & 127;
    int pos = lbase[b] + atomicAdd(&lcnt[b], 1);
    if (pos < BCAP) payload[(size_t)b * BCAP + pos] = (unsigned)s | ((unsigned)dl << 24);
  }
}

// Per-bucket GAT softmax in LDS; recomputes the logit from hg (hg[dst] staged
// in LDS, hg[src] from L2) and writes scoreL + per-block min/max partial
// (plain store; no contended atomics).
__global__ __launch_bounds__(256) void k_esoftmax(const unsigned* __restrict__ payload, const int* __restrict__ gcnt,
                                                  const float* __restrict__ hg, const float* __restrict__ asrc,
                                                  const float* __restrict__ adst, const float* __restrict__ gb,
                                                  float* __restrict__ scoreL, uint2* __restrict__ pmmL) {
  __shared__ unsigned mS[128];
  __shared__ float dS[128];
  __shared__ float nS[128];
  __shared__ float hgl[128];
  __shared__ unsigned pw[8];
  int b = blockIdx.x;
  int tid = threadIdx.x;
  if (tid < 128) {
    mS[tid] = 0u; dS[tid] = 0.f; nS[tid] = 0.f;
    int g = b * 128 + tid;
    hgl[tid] = (g < N) ? hg[g] : 0.f;
  }
  __syncthreads();
  float as = asrc[0], ad = adst[0];
  int cnt = min(gcnt[b], BCAP);
  const unsigned* bp = payload + (size_t)b * BCAP;
  for (int i = tid; i < cnt; i += 256) {
    unsigned r = bp[i];
    int s = (int)(r & 0xFFFFFFu), dl = (int)(r >> 24);
    float z = as * hg[s] + ad * hgl[dl];
    float ev = (z > 0.f) ? z : 0.2f * z;
    atomicMax(&mS[dl], enc_f(ev));
  }
  __syncthreads();
  for (int i = tid; i < cnt; i += 256) {
    unsigned r = bp[i];
    int s = (int)(r & 0xFFFFFFu), dl = (int)(r >> 24);
    float h = hg[s];
    float z = as * h + ad * hgl[dl];
    float ev = (z > 0.f) ? z : 0.2f * z;
    float ex = expf(ev - dec_f(mS[dl]));
    atomicAdd(&dS[dl], ex);
    atomicAdd(&nS[dl], ex * h);
  }
  __syncthreads();
  unsigned vmx = 0u, vmn = 0xFFFFFFFFu;
  if (tid < 128) {
    int dst = b * 128 + tid;
    if (dst < N) {
      float sl = nS[tid] / fmaxf(dS[tid], 1e-16f) + gb[0];
      scoreL[dst] = sl;
      unsigned e = enc_f(sl);
      vmx = e; vmn = e;
    }
  }
#pragma unroll
  for (int off = 32; off; off >>= 1) {
    vmx = max(vmx, (unsigned)__shfl_xor((int)vmx, off));
    vmn = min(vmn, (unsigned)__shfl_xor((int)vmn, off));
  }
  if ((tid & 63) == 0) { pw[(tid >> 6) * 2] = vmx; pw[(tid >> 6) * 2 + 1] = vmn; }
  __syncthreads();
  if (tid == 0) {
    unsigned a = max(max(pw[0], pw[2]), max(pw[4], pw[6]));
    unsigned c = min(min(pw[1], pw[3]), min(pw[5], pw[7]));
    pmmL[b] = make_uint2(a, c);
  }
}

// single-block reduce of per-block minmax partials -> mm[maxF,maxL,minF,minL]
__global__ __launch_bounds__(1024) void k_mm_reduce(const uint2* __restrict__ pmmF, const uint2* __restrict__ pmmL,
                                                    unsigned* __restrict__ mm) {
  __shared__ unsigned s[4][16];
  int t = threadIdx.x;
  unsigned mxF = 0u, mnF = 0xFFFFFFFFu, mxL = 0u, mnL = 0xFFFFFFFFu;
  for (int i = t; i < NSC64; i += 1024) {
    uint2 v = pmmF[i];
    mxF = max(mxF, v.x); mnF = min(mnF, v.y);
  }
  for (int i = t; i < NBK; i += 1024) {
    uint2 v = pmmL[i];
    mxL = max(mxL, v.x); mnL = min(mnL, v.y);
  }
#pragma unroll
  for (int off = 32; off; off >>= 1) {
    mxF = max(mxF, (unsigned)__shfl_xor((int)mxF, off));
    mnF = min(mnF, (unsigned)__shfl_xor((int)mnF, off));
    mxL = max(mxL, (unsigned)__shfl_xor((int)mxL, off));
    mnL = min(mnL, (unsigned)__shfl_xor((int)mnL, off));
  }
  int w = t >> 6;
  if ((t & 63) == 0) { s[0][w] = mxF; s[1][w] = mnF; s[2][w] = mxL; s[3][w] = mnL; }
  __syncthreads();
  if (t == 0) {
    unsigned a = 0u, b = 0xFFFFFFFFu, c = 0u, d = 0xFFFFFFFFu;
    for (int i = 0; i < 16; ++i) {
      a = max(a, s[0][i]); b = min(b, s[1][i]);
      c = max(c, s[2][i]); d = min(d, s[3][i]);
    }
    mm[0] = a; mm[2] = b; mm[1] = c; mm[3] = d;
  }
}

// ========== exact top-k ranking, both views per launch (blockIdx.y) ==========
__global__ __launch_bounds__(256) void k_bucket_hist2(const float* __restrict__ sc2, const unsigned* __restrict__ mm,
                                                      int* __restrict__ bucket2, int* __restrict__ hist2) {
  int v = blockIdx.y;
  int n = blockIdx.x * 256 + threadIdx.x;
  if (n >= N) return;
  const float* sc = sc2 + (size_t)v * N;
  float smax = dec_f(mm[v]), smin = dec_f(mm[2 + v]);
  float range = smax - smin;
  float scale = (range > 0.f) ? ((float)NB / range) : 0.f;
  float t = (smax - sc[n]) * scale;
  int b = (int)t;
  b = b < 0 ? 0 : (b > NB - 1 ? NB - 1 : b);
  bucket2[(size_t)v * N + n] = b;
  atomicAdd(&hist2[v * NB + b], 1);
}

__global__ __launch_bounds__(256) void k_bucket_scatter2(const int* __restrict__ bucket2, const int* __restrict__ start2,
                                                         int* __restrict__ cur2, int* __restrict__ slot2) {
  int v = blockIdx.y;
  int n = blockIdx.x * 256 + threadIdx.x;
  if (n >= N) return;
  int b = bucket2[(size_t)v * N + n];
  slot2[(size_t)v * N + start2[v * NB + b] + atomicAdd(&cur2[v * NB + b], 1)] = n;
}

// Bucket-centric exact ranking: one wave per bucket, keys staged in LDS once.
__global__ __launch_bounds__(64) void k_bucket_rank3(const float* __restrict__ sc2, const int* __restrict__ start2,
                                                     const int* __restrict__ hist2, const int* __restrict__ slot2,
                                                     int* __restrict__ rank2, int* __restrict__ sorted2) {
  __shared__ unsigned long long keys[RMAX];
  int v = blockIdx.y;
  int b = blockIdx.x;
  int st = start2[v * NB + b], cnt = hist2[v * NB + b];
  if (cnt == 0) return;
  const float* sc = sc2 + (size_t)v * N;
  const int* slot = slot2 + (size_t)v * N;
  int* rank = rank2 + (size_t)v * N;
  int* sorted = sorted2 + (size_t)v * N;
  int tid = threadIdx.x;
  if (cnt <= RMAX) {
    for (int i = tid; i < cnt; i += 64) {
      int m = slot[st + i];
      keys[i] = (((unsigned long long)(~enc_f(sc[m]))) << 32) | (unsigned)m;
    }
    __syncthreads();
    for (int i = tid; i < cnt; i += 64) {
      unsigned long long mykey = keys[i];
      int r = 0;
      for (int j = 0; j < cnt; ++j) r += (keys[j] < mykey) ? 1 : 0;
      int m = (int)(mykey & 0xFFFFFFFFu);
      rank[m] = st + r;
      sorted[st + r] = m;
    }
  } else {  // degenerate-distribution fallback
    for (int i = tid; i < cnt; i += 64) {
      int m = slot[st + i];
      unsigned long long mykey = (((unsigned long long)(~enc_f(sc[m]))) << 32) | (unsigned)m;
      int r = 0;
      for (int j = 0; j < cnt; ++j) {
        int mj = slot[st + j];
        unsigned long long k = (((unsigned long long)(~enc_f(sc[mj]))) << 32) | (unsigned)mj;
        r += (k < mykey) ? 1 : 0;
      }
      rank[m] = st + r;
      sorted[st + r] = m;
    }
  }
}

// ======================= union mapping =======================
__global__ __launch_bounds__(1024) void k_union_chunksum(const int* __restrict__ rankF, const int* __restrict__ rankL,
                                                         int* __restrict__ csum) {
  __shared__ int red[1024];
  int t = threadIdx.x; int i = blockIdx.x * 1024 + t;
  int u = (i < N) ? (((rankF[i] < KSEL) || (rankL[i] < KSEL)) ? 1 : 0) : 0;
  red[t] = u; __syncthreads();
  for (int off = 512; off; off >>= 1) { if (t < off) red[t] += red[t + off]; __syncthreads(); }
  if (t == 0) csum[blockIdx.x] = red[0];
}

__global__ __launch_bounds__(1024) void k_union_map(const int* __restrict__ rankF, const int* __restrict__ rankL,
                                                    const int* __restrict__ cstart, const int* __restrict__ batch,
                                                    int* __restrict__ mapping, float* __restrict__ outBatch) {
  __shared__ int sums[1024];
  int t = threadIdx.x; int i = blockIdx.x * 1024 + t;
  int u = (i < N) ? (((rankF[i] < KSEL) || (rankL[i] < KSEL)) ? 1 : 0) : 0;
  sums[t] = u; __syncthreads();
  for (int off = 1; off < 1024; off <<= 1) {
    int v = (t >= off) ? sums[t - off] : 0;
    __syncthreads();
    sums[t] += v;
    __syncthreads();
  }
  if (i < N) {
    mapping[i] = u ? (cstart[blockIdx.x] + sums[t] - 1) : -1;
    outBatch[i] = u ? (float)batch[i] : -1.0f;
  }
}

// merged: edge remap (blocks [0,EB)) + zero non-union Fp rows (blocks [EB,EB+ZB))
__global__ __launch_bounds__(256) void k_edge_zero(const int* __restrict__ ei, const int* __restrict__ mapping,
                                                   float* __restrict__ outE, float* __restrict__ Fp) {
  int b = blockIdx.x;
  if (b < EB) {
    int e = b * 256 + threadIdx.x;
    if (e >= E_) return;
    int m0 = mapping[ei[e]], m1 = mapping[ei[E_ + e]];
    bool valid = (m0 >= 0) && (m1 >= 0);
    outE[e] = valid ? (float)m0 : -1.f;
    outE[E_ + e] = valid ? (float)m1 : -1.f;
  } else {
    int i = (b - EB) * 256 + threadIdx.x;  // over N*32 float4s
    int n = i >> 5;
    if (n < N && mapping[n] < 0) ((float4*)Fp)[i] = make_float4(0.f, 0.f, 0.f, 0.f);
  }
}

// ======================= fused GCN transform + scatter (MFMA) =======================
// Fp[tgtL[i]] (+)= relu( x[srcL[i]] @ tw + tb + q*SW + (p-q)*HW[cid[srcL[i]]] )
// bf16 MFMA version: compute out^T tiles via D = twT(16o x 32k) . xT(32k x 16n)
// with mfma_f32_16x16x32_bf16. C/D layout (m89-verified): col=lane&15 -> node,
// row=(lane>>4)*4+reg -> 4 consecutive out-channels => coalesced float4 stores.
// x staged in LDS as bf16 [64][128] with XOR swizzle byte^=((row&7)<<4) to break
// the 16-way bank conflict on the stride-256B ds_read_b128 B-frag reads (T2).
// All 4 B-frags preloaded before the MFMA chain (ds_read latency off the
// critical path); twT (bf16, pre-transposed) read straight from global (L1/L2).
__global__ __launch_bounds__(256, 4) void k_fuse64(const float* __restrict__ x, const unsigned short* __restrict__ twT,
                                                   const float* __restrict__ tb, const float* __restrict__ SW,
                                                   const float* __restrict__ HW, const float* __restrict__ gdot,
                                                   const float* __restrict__ aDot, const int* __restrict__ cid,
                                                   const int* __restrict__ srcL, const int* __restrict__ tgtL,
                                                   const float* __restrict__ attb, const int* __restrict__ rankF,
                                                   float* __restrict__ Fp, int accum) {
  __shared__ __align__(16) unsigned xw[64 * 64];  // 64 rows x 128 bf16 cols, 16 KB, swizzled
  __shared__ float pq[64 * 2];
  __shared__ int mt[64 * 2];
  __shared__ int ft[64];
  int tid = threadIdx.x;
  int base = blockIdx.x * 64;
  if (tid < 64) {
    int ws = srcL[base + tid];
    int cc = cid[ws];
    int tg = tgtL[base + tid];
    mt[tid * 2] = cc;
    mt[tid * 2 + 1] = tg;
    ft[tid] = (rankF[tg] < KSEL) ? 1 : 0;
    float s = aDot[ws] + gdot[cc] + attb[0];
    float mx = fmaxf(s, 0.f);
    float esm = expf(s - mx), eom = expf(-mx);
    float dn = esm + 255.f * eom;
    pq[tid * 2] = esm / dn;
    pq[tid * 2 + 1] = eom / dn;
  }
  // stage 64 x-rows as bf16 (2048 float4 loads -> 2048 uint2 LDS writes)
#pragma unroll
  for (int k = 0; k < 8; ++k) {
    int i = k * 256 + tid;
    int r = i >> 5, c4 = i & 31;
    int ws = srcL[base + r];
    float4 v = ((const float4*)(x + (size_t)ws * D))[c4];
    uint2 pk;
    pk.x = (unsigned)f2bf(v.x) | ((unsigned)f2bf(v.y) << 16);
    pk.y = (unsigned)f2bf(v.z) | ((unsigned)f2bf(v.w) << 16);
    int u2 = r * 32 + (c4 ^ ((r & 7) << 1));  // byte = r*256 + ((c4*8) ^ ((r&7)<<4))
    ((uint2*)xw)[u2] = pk;
  }
  __syncthreads();

  int w = tid >> 6;        // wave 0..3 -> node rows w*16 .. w*16+15
  int l = tid & 63;
  int nl = l & 15;         // node within tile (D col)
  int khalf = l >> 4;      // k-block / out-ch subrow selector
  int row = w * 16 + nl;   // LDS x row this lane's B-frags come from

  f32x4 acc[8] = {};       // 8 out-ch tiles of 16 (full 128 out-channels)
  const char* xbase = (const char*)xw + row * 256;
  unsigned rsw = (unsigned)((row & 7) << 4);
  bf16x8 bfr[4];
#pragma unroll
  for (int ks = 0; ks < 4; ++ks)
    bfr[ks] = *(const bf16x8*)(xbase + (((unsigned)(ks * 64 + khalf * 16)) ^ rsw));
#pragma unroll
  for (int ks = 0; ks < 4; ++ks) {
#pragma unroll
    for (int ot = 0; ot < 8; ++ot) {
      // A-frag: twT[ot*16 + nl][ks*32 + khalf*8 .. +7] (16 B from L1/L2)
      bf16x8 afrag = *(const bf16x8*)(twT + (size_t)(ot * 16 + nl) * D + ks * 32 + khalf * 8);
      acc[ot] = __builtin_amdgcn_mfma_f32_16x16x32_bf16(afrag, bfr[ks], acc[ot], 0, 0, 0);
    }
  }

  // epilogue: lane owns node (w*16+nl), channels ot*16 + khalf*4 .. +3
  float p = pq[row * 2], q = pq[row * 2 + 1];
  int cc = mt[row * 2];
  int tgt = mt[row * 2 + 1];
  int doAcc = accum && ft[row];
#pragma unroll
  for (int ot = 0; ot < 8; ++ot) {
    int ch = ot * 16 + khalf * 4;
    float4 tbv = *(const float4*)(tb + ch);
    float4 swv = *(const float4*)(SW + ch);
    float4 hw = *(const float4*)(HW + (size_t)cc * D + ch);
    float4 o;
    o.x = fmaxf(acc[ot][0] + tbv.x + q * swv.x + (p - q) * hw.x, 0.f);
    o.y = fmaxf(acc[ot][1] + tbv.y + q * swv.y + (p - q) * hw.y, 0.f);
    o.z = fmaxf(acc[ot][2] + tbv.z + q * swv.z + (p - q) * hw.z, 0.f);
    o.w = fmaxf(acc[ot][3] + tbv.w + q * swv.w + (p - q) * hw.w, 0.f);
    float4* dst = (float4*)(Fp + (size_t)tgt * D + ch);
    if (doAcc) {
      float4 old = *dst;
      o.x = (o.x + old.x) * 0.5f;
      o.y = (o.y + old.y) * 0.5f;
      o.z = (o.z + old.z) * 0.5f;
      o.w = (o.w + old.w) * 0.5f;
    }
    *dst = o;
  }
}

// ======================= launcher =======================
extern "C" void kernel_launch(void* const* d_in, const int* in_sizes, int n_in,
                              void* d_out, int out_size, void* d_ws, size_t ws_size,
                              hipStream_t stream) {
  const float* x   = (const float*)d_in[0];
  const int* ei    = (const int*)d_in[1];
  const int* batch = (const int*)d_in[2];
  const int* cid   = (const int*)d_in[3];
  const float* w1  = (const float*)d_in[4];
  const float* b1  = (const float*)d_in[5];
  const float* w2  = (const float*)d_in[6];
  const float* b2  = (const float*)d_in[7];
  const float* gw  = (const float*)d_in[8];
  const float* gas = (const float*)d_in[9];
  const float* gad = (const float*)d_in[10];
  const float* gb  = (const float*)d_in[11];
  const float* wa  = (const float*)d_in[12];
  const float* wb  = (const float*)d_in[13];
  const float* ab  = (const float*)d_in[14];
  const float* tw  = (const float*)d_in[15];
  const float* tb  = (const float*)d_in[16];
  (void)in_sizes; (void)n_in; (void)ws_size; (void)out_size;

  char* p = (char*)d_ws;
  auto alloc = [&](size_t bytes) -> char* {
    char* r = p;
    p += (bytes + 255) & ~(size_t)255;
    return r;
  };
  // ---- zero-init region ----
  int* ccount    = (int*)alloc(C_ * 4);
  int* ccur      = (int*)alloc(C_ * 4);
  unsigned* mm   = (unsigned*)alloc(16);                // [maxF,maxL,minF,minL]
  int* hist2     = (int*)alloc(2 * NB * 4);
  int* cur2      = (int*)alloc(2 * NB * 4);
  float* Hc      = (float*)alloc((size_t)C_ * D * 4);   // atomic accumulator
  int* gcnt      = (int*)alloc(NBK * 4);
  size_t zeroBytes = (size_t)(p - (char*)d_ws);
  // ---- rest (fully written before read) ----
  int* cstart   = (int*)alloc(C_ * 4);
  int* cslot    = (int*)alloc((size_t)N * 4);
  float* gdot   = (float*)alloc(C_ * 4);
  float* SW     = (float*)alloc(D * 4);
  float* HW     = (float*)alloc((size_t)C_ * D * 4);
  unsigned short* twT = (unsigned short*)alloc((size_t)D * D * 2);
  float* score2 = (float*)alloc((size_t)2 * N * 4);     // [scoreF | scoreL]
  float* hg     = (float*)alloc((size_t)N * 4);
  float* aDot   = (float*)alloc((size_t)N * 4);
  unsigned* payload = (unsigned*)alloc((size_t)NBK * BCAP * 4);
  uint2* pmmF   = (uint2*)alloc((size_t)NSC64 * 8);
  uint2* pmmL   = (uint2*)alloc((size_t)NBK * 8);
  int* bucket2  = (int*)alloc((size_t)2 * N * 4);
  int* start2   = (int*)alloc(2 * NB * 4);
  int* slot2    = (int*)alloc((size_t)2 * N * 4);
  int* sorted2  = (int*)alloc((size_t)2 * N * 4);
  int* rank2    = (int*)alloc((size_t)2 * N * 4);
  int* csums    = (int*)alloc(NCHUNK * 4);
  int* cstarts  = (int*)alloc(NCHUNK * 4);
  int* mapping  = (int*)alloc((size_t)N * 4);

  float* scoreF = score2;
  float* scoreL = score2 + N;
  int* sortedF  = sorted2;
  int* sortedL  = sorted2 + N;
  int* rankF    = rank2;
  int* rankL    = rank2 + N;

  float* outF = (float*)d_out;             // [N, D]
  float* outE = outF + (size_t)N * D;      // [2, E]  (fully written by k_edge_zero)
  float* outB = outE + (size_t)2 * E_;     // [N]     (fully written by k_union_map)

  hipMemsetAsync(d_ws, 0, zeroBytes, stream);
  // outF: union rows fully written by the two fuse launches (store / cond-accum);
  // non-union rows zeroed by k_edge_zero -> no 51 MB memset.

  // cluster means + derived (+ twT transpose folded into k_S_SW_HW grid)
  k_hist_cluster<<<(N + 255) / 256, 256, 0, stream>>>(cid, ccount);
  k_scan_small<<<1, 1024, 0, stream>>>(ccount, cstart, C_);
  k_scatter_cluster<<<(N + 255) / 256, 256, 0, stream>>>(cid, cstart, ccur, cslot);
  k_cluster_partial<<<C_ * CSEG, 128, 0, stream>>>(x, cstart, ccount, cslot, Hc);
  k_mean_gdot<<<C_, 128, 0, stream>>>(ccount, wb, Hc, gdot);
  k_S_SW_HW<<<C_ + 1 + D, 128, 0, stream>>>(Hc, tw, SW, HW, twT);

  // fused per-node scores (MLP + GAT projections + minmax partials) + edge softmax
  k_score64<<<NSC64, 512, 0, stream>>>(x, w1, b1, w2, b2, gw, wa, scoreF, hg, aDot, pmmF);
  k_escatter<<<(E_ + 8191) / 8192, 1024, 0, stream>>>(ei, gcnt, payload);
  k_esoftmax<<<NBK, 256, 0, stream>>>(payload, gcnt, hg, gas, gad, gb, scoreL, pmmL);
  k_mm_reduce<<<1, 1024, 0, stream>>>(pmmF, pmmL, mm);

  // exact ranking, both views per launch (minmax folded into producers + 1-block reduce)
  dim3 g2((N + 255) / 256, 2);
  k_bucket_hist2<<<g2, 256, 0, stream>>>(score2, mm, bucket2, hist2);
  k_scan_small<<<2, 1024, 0, stream>>>(hist2, start2, NB);
  k_bucket_scatter2<<<g2, 256, 0, stream>>>(bucket2, start2, cur2, slot2);
  dim3 gr(NB, 2);
  k_bucket_rank3<<<gr, 64, 0, stream>>>(score2, start2, hist2, slot2, rank2, sorted2);

  // union mapping + edge remap + batch + zero non-union rows (merged)
  k_union_chunksum<<<NCHUNK, 1024, 0, stream>>>(rankF, rankL, csums);
  k_scan_small<<<1, 1024, 0, stream>>>(csums, cstarts, NCHUNK);
  k_union_map<<<NCHUNK, 1024, 0, stream>>>(rankF, rankL, cstarts, batch, mapping, outB);
  k_edge_zero<<<EB + ZB, 256, 0, stream>>>(ei, mapping, outE, outF);

  // fused features: launch 1 pure-stores (feat rows); launch 2 stores or
  // accumulates+halves (local rows) depending on feat membership.
  k_fuse64<<<KSEL / 64, 256, 0, stream>>>(x, twT, tb, SW, HW, gdot, aDot, cid, sortedL, sortedF, ab, rankF, outF, 0);
  k_fuse64<<<KSEL / 64, 256, 0, stream>>>(x, twT, tb, SW, HW, gdot, aDot, cid, sortedF, sortedL, ab, rankF, outF, 1);
}

// Round 9
// 528.101 us; speedup vs baseline: 2.6789x; 2.4679x over previous
//
#include <hip/hip_runtime.h>
#include <hip/hip_bf16.h>
#include <stdint.h>

#define N 100000
#define E_ 1600000
#define D 128
#define C_ 256
#define HID 64
#define KSEL 80000
#define NB 4096
#define CHUNK 1024
#define NCHUNK ((N + CHUNK - 1) / CHUNK)   // 98
#define CSEG 32                            // segments per cluster for mean reduction
#define NBK 782                            // ceil(N/128) dst-buckets of 128 nodes
#define BCAP 2560                          // per-bucket capacity (avg 2046 + >11 sigma)
#define RMAX 2048                          // LDS key capacity for in-bucket ranking
#define NSC64 ((N + 63) / 64)              // 1563 score blocks
#define EB ((E_ + 255) / 256)              // 6250 edge blocks
#define ZB ((N * 32 + 255) / 256)          // 12500 zero-row blocks

typedef __attribute__((ext_vector_type(8))) short bf16x8;
typedef __attribute__((ext_vector_type(4))) float f32x4;

// ---- ordered-float encoding (monotonic increasing uint) ----
__device__ __forceinline__ unsigned enc_f(float f) {
  unsigned b = __float_as_uint(f);
  return (b & 0x80000000u) ? ~b : (b | 0x80000000u);
}
__device__ __forceinline__ float dec_f(unsigned u) {
  unsigned b = (u & 0x80000000u) ? (u ^ 0x80000000u) : ~u;
  return __uint_as_float(b);
}

// fp32 -> bf16 round-to-nearest-even (finite inputs)
__device__ __forceinline__ unsigned short f2bf(float f) {
  unsigned u = __float_as_uint(f);
  unsigned r = u + 0x7FFFu + ((u >> 16) & 1u);
  return (unsigned short)(r >> 16);
}

// ======================= cluster CSR + means =======================
__global__ __launch_bounds__(256) void k_hist_cluster(const int* __restrict__ cid, int* __restrict__ ccount) {
  int n = blockIdx.x * 256 + threadIdx.x;
  if (n < N) atomicAdd(&ccount[cid[n]], 1);
}

// generic small scan; block b scans in[b*n .. b*n+n) -> out exclusive
__global__ __launch_bounds__(1024) void k_scan_small(const int* __restrict__ in0, int* __restrict__ out0, int n) {
  __shared__ int sums[1024];
  const int* in = in0 + (size_t)blockIdx.x * n;
  int* out = out0 + (size_t)blockIdx.x * n;
  int t = threadIdx.x;
  int per = (n + 1023) / 1024;
  int base = t * per;
  int loc = 0;
  for (int k = 0; k < per; ++k) { int i = base + k; if (i < n) loc += in[i]; }
  sums[t] = loc; __syncthreads();
  for (int off = 1; off < 1024; off <<= 1) {
    int v = (t >= off) ? sums[t - off] : 0;
    __syncthreads();
    sums[t] += v;
    __syncthreads();
  }
  int run = (t == 0) ? 0 : sums[t - 1];
  for (int k = 0; k < per; ++k) { int i = base + k; if (i < n) { out[i] = run; run += in[i]; } }
}

__global__ __launch_bounds__(256) void k_scatter_cluster(const int* __restrict__ cid, const int* __restrict__ cstart,
                                                         int* __restrict__ ccur, int* __restrict__ cslot) {
  int n = blockIdx.x * 256 + threadIdx.x;
  if (n < N) {
    int c = cid[n];
    int p = cstart[c] + atomicAdd(&ccur[c], 1);
    cslot[p] = n;
  }
}

__global__ __launch_bounds__(128) void k_cluster_partial(const float* __restrict__ x, const int* __restrict__ cstart,
                                                         const int* __restrict__ ccount, const int* __restrict__ cslot,
                                                         float* __restrict__ Hc) {
  int c = blockIdx.x >> 5;
  int s = blockIdx.x & (CSEG - 1);
  int d = threadIdx.x;
  int st = cstart[c], cnt = ccount[c];
  int seg = (cnt + CSEG - 1) / CSEG;
  int lo = s * seg;
  int hi = min(cnt, lo + seg);
  if (lo >= hi) return;
  float acc = 0.f;
  int k = lo;
  for (; k + 2 <= hi; k += 2) {
    int n0 = cslot[st + k], n1 = cslot[st + k + 1];
    float v0 = x[(size_t)n0 * D + d];
    float v1 = x[(size_t)n1 * D + d];
    acc += v0 + v1;
  }
  if (k < hi) acc += x[(size_t)cslot[st + k] * D + d];
  atomicAdd(&Hc[(size_t)c * D + d], acc);
}

// divide Hc by counts, then gdot[c] = Hc[c] . wb  (merged, one launch)
__global__ __launch_bounds__(128) void k_mean_gdot(const int* __restrict__ ccount, const float* __restrict__ wb,
                                                   float* __restrict__ Hc, float* __restrict__ gdot) {
  __shared__ float red[128];
  int c = blockIdx.x, d = threadIdx.x;
  float hv = Hc[(size_t)c * D + d] / (float)max(ccount[c], 1);
  Hc[(size_t)c * D + d] = hv;
  red[d] = hv * wb[d];
  __syncthreads();
  if (d < 64) {
    float v = red[d] + red[d + 64];
    for (int off = 32; off; off >>= 1) v += __shfl_down(v, off);
    if (d == 0) gdot[c] = v;
  }
}

// block 0: S = sum_c Hc[c], SW = S @ tw ; blocks 1..C_: HW[b-1] = Hc[b-1] @ tw ;
// blocks C_+1 .. C_+D: twT row (b-C_-1) = bf16 transpose of tw (folded k_twT).
__global__ __launch_bounds__(128) void k_S_SW_HW(const float* __restrict__ Hc, const float* __restrict__ tw,
                                                 float* __restrict__ SW, float* __restrict__ HW,
                                                 unsigned short* __restrict__ twT) {
  __shared__ float Sl[128];
  int b = blockIdx.x, t = threadIdx.x;
  if (b == 0) {
    float s = 0.f;
    for (int c = 0; c < C_; ++c) s += Hc[(size_t)c * D + t];
    Sl[t] = s;
    __syncthreads();
    float acc = 0.f;
    for (int d = 0; d < D; ++d) acc = fmaf(Sl[d], tw[(size_t)d * D + t], acc);
    SW[t] = acc;
  } else if (b <= C_) {
    const float* src = Hc + (size_t)(b - 1) * D;
    float acc = 0.f;
    for (int d = 0; d < D; ++d) acc = fmaf(src[d], tw[(size_t)d * D + t], acc);
    HW[(size_t)(b - 1) * D + t] = acc;
  } else {
    int k = b - C_ - 1;   // 0..127 ; twT[o][k] = bf16(tw[k][o]), o = t (coalesced read)
    twT[(size_t)t * D + k] = f2bf(tw[(size_t)k * D + t]);
  }
}

// ======== fused per-node scores: MLP (feature view) + GAT h/aDot ========
// fp32 throughout (scoreF drives an exact top-K selection). PROVEN round-6
// configuration (54.2 us, VGPR 44, zero spill): 256 threads, 4 rows x 4 cols
// per thread, w1 slabs register-prefetched, plain inline LDS reads, pmmF
// plain-store tail. ROUND-7/8 LESSON: widening to 512 threads with ANY
// launch_bounds min-occupancy arg capped VGPR (32/64) below the loop's ~84
// need -> GBs of scratch spill traffic, 15x slowdown. Do not re-widen.
__global__ __launch_bounds__(256, 4) void k_score64(const float* __restrict__ x, const float* __restrict__ w1,
                                                    const float* __restrict__ b1, const float* __restrict__ w2,
                                                    const float* __restrict__ b2, const float* __restrict__ gw,
                                                    const float* __restrict__ wa, float* __restrict__ scoreF,
                                                    float* __restrict__ hg, float* __restrict__ aDot,
                                                    uint2* __restrict__ pmmF) {
  __shared__ float xld[64 * D];  // 32 KB, swizzled by float4 chunk
  int tid = threadIdx.x;
  int base = blockIdx.x * 64;
#pragma unroll
  for (int k = 0; k < 8; ++k) {
    int i = k * 256 + tid;
    int r = i >> 5, cc = i & 31;
    int n = base + r;
    float4 v = make_float4(0.f, 0.f, 0.f, 0.f);
    if (n < N) v = ((const float4*)(x + (size_t)n * D))[cc];
    ((float4*)xld)[r * 32 + (cc ^ (r & 7))] = v;
  }
  __syncthreads();

  int rg = tid >> 4;        // 16 row-groups of 4 rows
  int cg = tid & 15;        // 16 col-groups of 4 hid cols
  int r0 = rg * 4;
  int c4 = cg * 4;
  float acc[4][4] = {};
  float4 wc0 = *(const float4*)(w1 + (size_t)0 * HID + c4);
  float4 wc1 = *(const float4*)(w1 + (size_t)1 * HID + c4);
  float4 wc2 = *(const float4*)(w1 + (size_t)2 * HID + c4);
  float4 wc3 = *(const float4*)(w1 + (size_t)3 * HID + c4);
  for (int d4 = 0; d4 < D; d4 += 4) {
    float4 wn0, wn1, wn2, wn3;
    if (d4 + 4 < D) {  // prefetch next w1 slab; used only after the 64-FMA block
      wn0 = *(const float4*)(w1 + (size_t)(d4 + 4) * HID + c4);
      wn1 = *(const float4*)(w1 + (size_t)(d4 + 5) * HID + c4);
      wn2 = *(const float4*)(w1 + (size_t)(d4 + 6) * HID + c4);
      wn3 = *(const float4*)(w1 + (size_t)(d4 + 7) * HID + c4);
    } else {
      wn0 = wn1 = wn2 = wn3 = make_float4(0.f, 0.f, 0.f, 0.f);
    }
    int j = d4 >> 2;
#pragma unroll
    for (int rr = 0; rr < 4; ++rr) {
      int row = r0 + rr;
      float4 xv = ((const float4*)xld)[row * 32 + (j ^ (row & 7))];
      acc[rr][0] = fmaf(xv.x, wc0.x, acc[rr][0]);
      acc[rr][1] = fmaf(xv.x, wc0.y, acc[rr][1]);
      acc[rr][2] = fmaf(xv.x, wc0.z, acc[rr][2]);
      acc[rr][3] = fmaf(xv.x, wc0.w, acc[rr][3]);
      acc[rr][0] = fmaf(xv.y, wc1.x, acc[rr][0]);
      acc[rr][1] = fmaf(xv.y, wc1.y, acc[rr][1]);
      acc[rr][2] = fmaf(xv.y, wc1.z, acc[rr][2]);
      acc[rr][3] = fmaf(xv.y, wc1.w, acc[rr][3]);
      acc[rr][0] = fmaf(xv.z, wc2.x, acc[rr][0]);
      acc[rr][1] = fmaf(xv.z, wc2.y, acc[rr][1]);
      acc[rr][2] = fmaf(xv.z, wc2.z, acc[rr][2]);
      acc[rr][3] = fmaf(xv.z, wc2.w, acc[rr][3]);
      acc[rr][0] = fmaf(xv.w, wc3.x, acc[rr][0]);
      acc[rr][1] = fmaf(xv.w, wc3.y, acc[rr][1]);
      acc[rr][2] = fmaf(xv.w, wc3.z, acc[rr][2]);
      acc[rr][3] = fmaf(xv.w, wc3.w, acc[rr][3]);
    }
    wc0 = wn0; wc1 = wn1; wc2 = wn2; wc3 = wn3;
  }

  float4 b1v = *(const float4*)(b1 + c4);
  float4 w2v = *(const float4*)(w2 + c4);
  float bb = b2[0];
  unsigned vmx = 0u, vmn = 0xFFFFFFFFu;
#pragma unroll
  for (int rr = 0; rr < 4; ++rr) {
    float p = fmaxf(acc[rr][0] + b1v.x, 0.f) * w2v.x
            + fmaxf(acc[rr][1] + b1v.y, 0.f) * w2v.y
            + fmaxf(acc[rr][2] + b1v.z, 0.f) * w2v.z
            + fmaxf(acc[rr][3] + b1v.w, 0.f) * w2v.w;
#pragma unroll
    for (int off = 8; off; off >>= 1) p += __shfl_xor(p, off);  // 16-lane group reduce
    if (cg == 0) {
      int n = base + r0 + rr;
      if (n < N) {
        float sf = p + bb;
        scoreF[n] = sf;
        unsigned e = enc_f(sf);
        vmx = max(vmx, e);
        vmn = min(vmn, e);
      }
    }
  }
  // wave-level scoreF min/max (register-only; block combine at the end)
#pragma unroll
  for (int off = 32; off; off >>= 1) {
    vmx = max(vmx, (unsigned)__shfl_xor((int)vmx, off));
    vmn = min(vmn, (unsigned)__shfl_xor((int)vmn, off));
  }

  float4 gwa = *(const float4*)(gw + c4);
  float4 gwb = *(const float4*)(gw + 64 + c4);
  float4 waa = *(const float4*)(wa + c4);
  float4 wab = *(const float4*)(wa + 64 + c4);
#pragma unroll
  for (int rr = 0; rr < 4; ++rr) {
    int row = r0 + rr;
    float4 xa = ((const float4*)xld)[row * 32 + (cg ^ (row & 7))];
    float4 xb = ((const float4*)xld)[row * 32 + ((cg + 16) ^ (row & 7))];
    float hp = xa.x * gwa.x + xa.y * gwa.y + xa.z * gwa.z + xa.w * gwa.w
             + xb.x * gwb.x + xb.y * gwb.y + xb.z * gwb.z + xb.w * gwb.w;
    float ap = xa.x * waa.x + xa.y * waa.y + xa.z * waa.z + xa.w * waa.w
             + xb.x * wab.x + xb.y * wab.y + xb.z * wab.z + xb.w * wab.w;
#pragma unroll
    for (int off = 8; off; off >>= 1) {
      hp += __shfl_xor(hp, off);
      ap += __shfl_xor(ap, off);
    }
    if (cg == 0) {
      int n = base + row;
      if (n < N) { hg[n] = hp; aDot[n] = ap; }
    }
  }

  // block combine through (now-dead) xld; one plain store, no atomics
  __syncthreads();
  if ((tid & 63) == 0) {
    ((unsigned*)xld)[(tid >> 6) * 2] = vmx;
    ((unsigned*)xld)[(tid >> 6) * 2 + 1] = vmn;
  }
  __syncthreads();
  if (tid == 0) {
    const unsigned* xu = (const unsigned*)xld;
    unsigned a = max(max(xu[0], xu[2]), max(xu[4], xu[6]));
    unsigned b = min(min(xu[1], xu[3]), min(xu[5], xu[7]));
    pmmF[blockIdx.x] = make_uint2(a, b);
  }
}

// Bucket edges by dst>>7 with LDS-aggregated reservation. Payload is 4 B/edge
// (s | dl<<24); the GAT logit is recomputed bit-identically in k_esoftmax.
__global__ __launch_bounds__(1024) void k_escatter(const int* __restrict__ ei, int* __restrict__ gcnt,
                                                   unsigned* __restrict__ payload) {
  __shared__ int lcnt[NBK];
  __shared__ int lbase[NBK];
  int tid = threadIdx.x;
  for (int i = tid; i < NBK; i += 1024) lcnt[i] = 0;
  int e0 = blockIdx.x * 8192;
  int es[8], ed[8];
#pragma unroll
  for (int k = 0; k < 8; ++k) {
    int e = e0 + k * 1024 + tid;
    bool v = (e < E_);
    es[k] = v ? ei[e] : -1;
    ed[k] = v ? ei[E_ + e] : -1;
  }
  __syncthreads();
#pragma unroll
  for (int k = 0; k < 8; ++k)
    if (ed[k] >= 0) atomicAdd(&lcnt[ed[k] >> 7], 1);
  __syncthreads();
  for (int i = tid; i < NBK; i += 1024) {
    int c = lcnt[i];
    lbase[i] = c ? atomicAdd(&gcnt[i], c) : 0;
    lcnt[i] = 0;
  }
  __syncthreads();
#pragma unroll
  for (int k = 0; k < 8; ++k) {
    if (ed[k] < 0) continue;
    int s = es[k], d = ed[k];
    int b = d >> 7, dl = d & 127;
    int pos = lbase[b] + atomicAdd(&lcnt[b], 1);
    if (pos < BCAP) payload[(size_t)b * BCAP + pos] = (unsigned)s | ((unsigned)dl << 24);
  }
}

// Per-bucket GAT softmax in LDS; recomputes the logit from hg (hg[dst] staged
// in LDS, hg[src] from L2) and writes scoreL + per-block min/max partial
// (plain store; no contended atomics).
__global__ __launch_bounds__(256) void k_esoftmax(const unsigned* __restrict__ payload, const int* __restrict__ gcnt,
                                                  const float* __restrict__ hg, const float* __restrict__ asrc,
                                                  const float* __restrict__ adst, const float* __restrict__ gb,
                                                  float* __restrict__ scoreL, uint2* __restrict__ pmmL) {
  __shared__ unsigned mS[128];
  __shared__ float dS[128];
  __shared__ float nS[128];
  __shared__ float hgl[128];
  __shared__ unsigned pw[8];
  int b = blockIdx.x;
  int tid = threadIdx.x;
  if (tid < 128) {
    mS[tid] = 0u; dS[tid] = 0.f; nS[tid] = 0.f;
    int g = b * 128 + tid;
    hgl[tid] = (g < N) ? hg[g] : 0.f;
  }
  __syncthreads();
  float as = asrc[0], ad = adst[0];
  int cnt = min(gcnt[b], BCAP);
  const unsigned* bp = payload + (size_t)b * BCAP;
  for (int i = tid; i < cnt; i += 256) {
    unsigned r = bp[i];
    int s = (int)(r & 0xFFFFFFu), dl = (int)(r >> 24);
    float z = as * hg[s] + ad * hgl[dl];
    float ev = (z > 0.f) ? z : 0.2f * z;
    atomicMax(&mS[dl], enc_f(ev));
  }
  __syncthreads();
  for (int i = tid; i < cnt; i += 256) {
    unsigned r = bp[i];
    int s = (int)(r & 0xFFFFFFu), dl = (int)(r >> 24);
    float h = hg[s];
    float z = as * h + ad * hgl[dl];
    float ev = (z > 0.f) ? z : 0.2f * z;
    float ex = expf(ev - dec_f(mS[dl]));
    atomicAdd(&dS[dl], ex);
    atomicAdd(&nS[dl], ex * h);
  }
  __syncthreads();
  unsigned vmx = 0u, vmn = 0xFFFFFFFFu;
  if (tid < 128) {
    int dst = b * 128 + tid;
    if (dst < N) {
      float sl = nS[tid] / fmaxf(dS[tid], 1e-16f) + gb[0];
      scoreL[dst] = sl;
      unsigned e = enc_f(sl);
      vmx = e; vmn = e;
    }
  }
#pragma unroll
  for (int off = 32; off; off >>= 1) {
    vmx = max(vmx, (unsigned)__shfl_xor((int)vmx, off));
    vmn = min(vmn, (unsigned)__shfl_xor((int)vmn, off));
  }
  if ((tid & 63) == 0) { pw[(tid >> 6) * 2] = vmx; pw[(tid >> 6) * 2 + 1] = vmn; }
  __syncthreads();
  if (tid == 0) {
    unsigned a = max(max(pw[0], pw[2]), max(pw[4], pw[6]));
    unsigned c = min(min(pw[1], pw[3]), min(pw[5], pw[7]));
    pmmL[b] = make_uint2(a, c);
  }
}

// single-block reduce of per-block minmax partials -> mm[maxF,maxL,minF,minL]
__global__ __launch_bounds__(1024) void k_mm_reduce(const uint2* __restrict__ pmmF, const uint2* __restrict__ pmmL,
                                                    unsigned* __restrict__ mm) {
  __shared__ unsigned s[4][16];
  int t = threadIdx.x;
  unsigned mxF = 0u, mnF = 0xFFFFFFFFu, mxL = 0u, mnL = 0xFFFFFFFFu;
  for (int i = t; i < NSC64; i += 1024) {
    uint2 v = pmmF[i];
    mxF = max(mxF, v.x); mnF = min(mnF, v.y);
  }
  for (int i = t; i < NBK; i += 1024) {
    uint2 v = pmmL[i];
    mxL = max(mxL, v.x); mnL = min(mnL, v.y);
  }
#pragma unroll
  for (int off = 32; off; off >>= 1) {
    mxF = max(mxF, (unsigned)__shfl_xor((int)mxF, off));
    mnF = min(mnF, (unsigned)__shfl_xor((int)mnF, off));
    mxL = max(mxL, (unsigned)__shfl_xor((int)mxL, off));
    mnL = min(mnL, (unsigned)__shfl_xor((int)mnL, off));
  }
  int w = t >> 6;
  if ((t & 63) == 0) { s[0][w] = mxF; s[1][w] = mnF; s[2][w] = mxL; s[3][w] = mnL; }
  __syncthreads();
  if (t == 0) {
    unsigned a = 0u, b = 0xFFFFFFFFu, c = 0u, d = 0xFFFFFFFFu;
    for (int i = 0; i < 16; ++i) {
      a = max(a, s[0][i]); b = min(b, s[1][i]);
      c = max(c, s[2][i]); d = min(d, s[3][i]);
    }
    mm[0] = a; mm[2] = b; mm[1] = c; mm[3] = d;
  }
}

// ========== exact top-k ranking, both views per launch (blockIdx.y) ==========
__global__ __launch_bounds__(256) void k_bucket_hist2(const float* __restrict__ sc2, const unsigned* __restrict__ mm,
                                                      int* __restrict__ bucket2, int* __restrict__ hist2) {
  int v = blockIdx.y;
  int n = blockIdx.x * 256 + threadIdx.x;
  if (n >= N) return;
  const float* sc = sc2 + (size_t)v * N;
  float smax = dec_f(mm[v]), smin = dec_f(mm[2 + v]);
  float range = smax - smin;
  float scale = (range > 0.f) ? ((float)NB / range) : 0.f;
  float t = (smax - sc[n]) * scale;
  int b = (int)t;
  b = b < 0 ? 0 : (b > NB - 1 ? NB - 1 : b);
  bucket2[(size_t)v * N + n] = b;
  atomicAdd(&hist2[v * NB + b], 1);
}

__global__ __launch_bounds__(256) void k_bucket_scatter2(const int* __restrict__ bucket2, const int* __restrict__ start2,
                                                         int* __restrict__ cur2, int* __restrict__ slot2) {
  int v = blockIdx.y;
  int n = blockIdx.x * 256 + threadIdx.x;
  if (n >= N) return;
  int b = bucket2[(size_t)v * N + n];
  slot2[(size_t)v * N + start2[v * NB + b] + atomicAdd(&cur2[v * NB + b], 1)] = n;
}

// Bucket-centric exact ranking: one wave per bucket, keys staged in LDS once.
__global__ __launch_bounds__(64) void k_bucket_rank3(const float* __restrict__ sc2, const int* __restrict__ start2,
                                                     const int* __restrict__ hist2, const int* __restrict__ slot2,
                                                     int* __restrict__ rank2, int* __restrict__ sorted2) {
  __shared__ unsigned long long keys[RMAX];
  int v = blockIdx.y;
  int b = blockIdx.x;
  int st = start2[v * NB + b], cnt = hist2[v * NB + b];
  if (cnt == 0) return;
  const float* sc = sc2 + (size_t)v * N;
  const int* slot = slot2 + (size_t)v * N;
  int* rank = rank2 + (size_t)v * N;
  int* sorted = sorted2 + (size_t)v * N;
  int tid = threadIdx.x;
  if (cnt <= RMAX) {
    for (int i = tid; i < cnt; i += 64) {
      int m = slot[st + i];
      keys[i] = (((unsigned long long)(~enc_f(sc[m]))) << 32) | (unsigned)m;
    }
    __syncthreads();
    for (int i = tid; i < cnt; i += 64) {
      unsigned long long mykey = keys[i];
      int r = 0;
      for (int j = 0; j < cnt; ++j) r += (keys[j] < mykey) ? 1 : 0;
      int m = (int)(mykey & 0xFFFFFFFFu);
      rank[m] = st + r;
      sorted[st + r] = m;
    }
  } else {  // degenerate-distribution fallback
    for (int i = tid; i < cnt; i += 64) {
      int m = slot[st + i];
      unsigned long long mykey = (((unsigned long long)(~enc_f(sc[m]))) << 32) | (unsigned)m;
      int r = 0;
      for (int j = 0; j < cnt; ++j) {
        int mj = slot[st + j];
        unsigned long long k = (((unsigned long long)(~enc_f(sc[mj]))) << 32) | (unsigned)mj;
        r += (k < mykey) ? 1 : 0;
      }
      rank[m] = st + r;
      sorted[st + r] = m;
    }
  }
}

// ======================= union mapping =======================
__global__ __launch_bounds__(1024) void k_union_chunksum(const int* __restrict__ rankF, const int* __restrict__ rankL,
                                                         int* __restrict__ csum) {
  __shared__ int red[1024];
  int t = threadIdx.x; int i = blockIdx.x * 1024 + t;
  int u = (i < N) ? (((rankF[i] < KSEL) || (rankL[i] < KSEL)) ? 1 : 0) : 0;
  red[t] = u; __syncthreads();
  for (int off = 512; off; off >>= 1) { if (t < off) red[t] += red[t + off]; __syncthreads(); }
  if (t == 0) csum[blockIdx.x] = red[0];
}

__global__ __launch_bounds__(1024) void k_union_map(const int* __restrict__ rankF, const int* __restrict__ rankL,
                                                    const int* __restrict__ cstart, const int* __restrict__ batch,
                                                    int* __restrict__ mapping, float* __restrict__ outBatch) {
  __shared__ int sums[1024];
  int t = threadIdx.x; int i = blockIdx.x * 1024 + t;
  int u = (i < N) ? (((rankF[i] < KSEL) || (rankL[i] < KSEL)) ? 1 : 0) : 0;
  sums[t] = u; __syncthreads();
  for (int off = 1; off < 1024; off <<= 1) {
    int v = (t >= off) ? sums[t - off] : 0;
    __syncthreads();
    sums[t] += v;
    __syncthreads();
  }
  if (i < N) {
    mapping[i] = u ? (cstart[blockIdx.x] + sums[t] - 1) : -1;
    outBatch[i] = u ? (float)batch[i] : -1.0f;
  }
}

// merged: edge remap (blocks [0,EB)) + zero non-union Fp rows (blocks [EB,EB+ZB))
__global__ __launch_bounds__(256) void k_edge_zero(const int* __restrict__ ei, const int* __restrict__ mapping,
                                                   float* __restrict__ outE, float* __restrict__ Fp) {
  int b = blockIdx.x;
  if (b < EB) {
    int e = b * 256 + threadIdx.x;
    if (e >= E_) return;
    int m0 = mapping[ei[e]], m1 = mapping[ei[E_ + e]];
    bool valid = (m0 >= 0) && (m1 >= 0);
    outE[e] = valid ? (float)m0 : -1.f;
    outE[E_ + e] = valid ? (float)m1 : -1.f;
  } else {
    int i = (b - EB) * 256 + threadIdx.x;  // over N*32 float4s
    int n = i >> 5;
    if (n < N && mapping[n] < 0) ((float4*)Fp)[i] = make_float4(0.f, 0.f, 0.f, 0.f);
  }
}

// ======================= fused GCN transform + scatter (MFMA) =======================
// Fp[tgtL[i]] (+)= relu( x[srcL[i]] @ tw + tb + q*SW + (p-q)*HW[cid[srcL[i]]] )
// bf16 MFMA version: compute out^T tiles via D = twT(16o x 32k) . xT(32k x 16n)
// with mfma_f32_16x16x32_bf16. C/D layout (m89-verified): col=lane&15 -> node,
// row=(lane>>4)*4+reg -> 4 consecutive out-channels => coalesced float4 stores.
// x staged in LDS as bf16 [64][128] with XOR swizzle byte^=((row&7)<<4) to break
// the 16-way bank conflict on the stride-256B ds_read_b128 B-frag reads (T2).
// All 4 B-frags preloaded before the MFMA chain (ds_read latency off the
// critical path); twT (bf16, pre-transposed) read straight from global (L1/L2).
__global__ __launch_bounds__(256, 4) void k_fuse64(const float* __restrict__ x, const unsigned short* __restrict__ twT,
                                                   const float* __restrict__ tb, const float* __restrict__ SW,
                                                   const float* __restrict__ HW, const float* __restrict__ gdot,
                                                   const float* __restrict__ aDot, const int* __restrict__ cid,
                                                   const int* __restrict__ srcL, const int* __restrict__ tgtL,
                                                   const float* __restrict__ attb, const int* __restrict__ rankF,
                                                   float* __restrict__ Fp, int accum) {
  __shared__ __align__(16) unsigned xw[64 * 64];  // 64 rows x 128 bf16 cols, 16 KB, swizzled
  __shared__ float pq[64 * 2];
  __shared__ int mt[64 * 2];
  __shared__ int ft[64];
  int tid = threadIdx.x;
  int base = blockIdx.x * 64;
  if (tid < 64) {
    int ws = srcL[base + tid];
    int cc = cid[ws];
    int tg = tgtL[base + tid];
    mt[tid * 2] = cc;
    mt[tid * 2 + 1] = tg;
    ft[tid] = (rankF[tg] < KSEL) ? 1 : 0;
    float s = aDot[ws] + gdot[cc] + attb[0];
    float mx = fmaxf(s, 0.f);
    float esm = expf(s - mx), eom = expf(-mx);
    float dn = esm + 255.f * eom;
    pq[tid * 2] = esm / dn;
    pq[tid * 2 + 1] = eom / dn;
  }
  // stage 64 x-rows as bf16 (2048 float4 loads -> 2048 uint2 LDS writes)
#pragma unroll
  for (int k = 0; k < 8; ++k) {
    int i = k * 256 + tid;
    int r = i >> 5, c4 = i & 31;
    int ws = srcL[base + r];
    float4 v = ((const float4*)(x + (size_t)ws * D))[c4];
    uint2 pk;
    pk.x = (unsigned)f2bf(v.x) | ((unsigned)f2bf(v.y) << 16);
    pk.y = (unsigned)f2bf(v.z) | ((unsigned)f2bf(v.w) << 16);
    int u2 = r * 32 + (c4 ^ ((r & 7) << 1));  // byte = r*256 + ((c4*8) ^ ((r&7)<<4))
    ((uint2*)xw)[u2] = pk;
  }
  __syncthreads();

  int w = tid >> 6;        // wave 0..3 -> node rows w*16 .. w*16+15
  int l = tid & 63;
  int nl = l & 15;         // node within tile (D col)
  int khalf = l >> 4;      // k-block / out-ch subrow selector
  int row = w * 16 + nl;   // LDS x row this lane's B-frags come from

  f32x4 acc[8] = {};       // 8 out-ch tiles of 16 (full 128 out-channels)
  const char* xbase = (const char*)xw + row * 256;
  unsigned rsw = (unsigned)((row & 7) << 4);
  bf16x8 bfr[4];
#pragma unroll
  for (int ks = 0; ks < 4; ++ks)
    bfr[ks] = *(const bf16x8*)(xbase + (((unsigned)(ks * 64 + khalf * 16)) ^ rsw));
#pragma unroll
  for (int ks = 0; ks < 4; ++ks) {
#pragma unroll
    for (int ot = 0; ot < 8; ++ot) {
      // A-frag: twT[ot*16 + nl][ks*32 + khalf*8 .. +7] (16 B from L1/L2)
      bf16x8 afrag = *(const bf16x8*)(twT + (size_t)(ot * 16 + nl) * D + ks * 32 + khalf * 8);
      acc[ot] = __builtin_amdgcn_mfma_f32_16x16x32_bf16(afrag, bfr[ks], acc[ot], 0, 0, 0);
    }
  }

  // epilogue: lane owns node (w*16+nl), channels ot*16 + khalf*4 .. +3
  float p = pq[row * 2], q = pq[row * 2 + 1];
  int cc = mt[row * 2];
  int tgt = mt[row * 2 + 1];
  int doAcc = accum && ft[row];
#pragma unroll
  for (int ot = 0; ot < 8; ++ot) {
    int ch = ot * 16 + khalf * 4;
    float4 tbv = *(const float4*)(tb + ch);
    float4 swv = *(const float4*)(SW + ch);
    float4 hw = *(const float4*)(HW + (size_t)cc * D + ch);
    float4 o;
    o.x = fmaxf(acc[ot][0] + tbv.x + q * swv.x + (p - q) * hw.x, 0.f);
    o.y = fmaxf(acc[ot][1] + tbv.y + q * swv.y + (p - q) * hw.y, 0.f);
    o.z = fmaxf(acc[ot][2] + tbv.z + q * swv.z + (p - q) * hw.z, 0.f);
    o.w = fmaxf(acc[ot][3] + tbv.w + q * swv.w + (p - q) * hw.w, 0.f);
    float4* dst = (float4*)(Fp + (size_t)tgt * D + ch);
    if (doAcc) {
      float4 old = *dst;
      o.x = (o.x + old.x) * 0.5f;
      o.y = (o.y + old.y) * 0.5f;
      o.z = (o.z + old.z) * 0.5f;
      o.w = (o.w + old.w) * 0.5f;
    }
    *dst = o;
  }
}

// ======================= launcher =======================
extern "C" void kernel_launch(void* const* d_in, const int* in_sizes, int n_in,
                              void* d_out, int out_size, void* d_ws, size_t ws_size,
                              hipStream_t stream) {
  const float* x   = (const float*)d_in[0];
  const int* ei    = (const int*)d_in[1];
  const int* batch = (const int*)d_in[2];
  const int* cid   = (const int*)d_in[3];
  const float* w1  = (const float*)d_in[4];
  const float* b1  = (const float*)d_in[5];
  const float* w2  = (const float*)d_in[6];
  const float* b2  = (const float*)d_in[7];
  const float* gw  = (const float*)d_in[8];
  const float* gas = (const float*)d_in[9];
  const float* gad = (const float*)d_in[10];
  const float* gb  = (const float*)d_in[11];
  const float* wa  = (const float*)d_in[12];
  const float* wb  = (const float*)d_in[13];
  const float* ab  = (const float*)d_in[14];
  const float* tw  = (const float*)d_in[15];
  const float* tb  = (const float*)d_in[16];
  (void)in_sizes; (void)n_in; (void)ws_size; (void)out_size;

  char* p = (char*)d_ws;
  auto alloc = [&](size_t bytes) -> char* {
    char* r = p;
    p += (bytes + 255) & ~(size_t)255;
    return r;
  };
  // ---- zero-init region ----
  int* ccount    = (int*)alloc(C_ * 4);
  int* ccur      = (int*)alloc(C_ * 4);
  unsigned* mm   = (unsigned*)alloc(16);                // [maxF,maxL,minF,minL]
  int* hist2     = (int*)alloc(2 * NB * 4);
  int* cur2      = (int*)alloc(2 * NB * 4);
  float* Hc      = (float*)alloc((size_t)C_ * D * 4);   // atomic accumulator
  int* gcnt      = (int*)alloc(NBK * 4);
  size_t zeroBytes = (size_t)(p - (char*)d_ws);
  // ---- rest (fully written before read) ----
  int* cstart   = (int*)alloc(C_ * 4);
  int* cslot    = (int*)alloc((size_t)N * 4);
  float* gdot   = (float*)alloc(C_ * 4);
  float* SW     = (float*)alloc(D * 4);
  float* HW     = (float*)alloc((size_t)C_ * D * 4);
  unsigned short* twT = (unsigned short*)alloc((size_t)D * D * 2);
  float* score2 = (float*)alloc((size_t)2 * N * 4);     // [scoreF | scoreL]
  float* hg     = (float*)alloc((size_t)N * 4);
  float* aDot   = (float*)alloc((size_t)N * 4);
  unsigned* payload = (unsigned*)alloc((size_t)NBK * BCAP * 4);
  uint2* pmmF   = (uint2*)alloc((size_t)NSC64 * 8);
  uint2* pmmL   = (uint2*)alloc((size_t)NBK * 8);
  int* bucket2  = (int*)alloc((size_t)2 * N * 4);
  int* start2   = (int*)alloc(2 * NB * 4);
  int* slot2    = (int*)alloc((size_t)2 * N * 4);
  int* sorted2  = (int*)alloc((size_t)2 * N * 4);
  int* rank2    = (int*)alloc((size_t)2 * N * 4);
  int* csums    = (int*)alloc(NCHUNK * 4);
  int* cstarts  = (int*)alloc(NCHUNK * 4);
  int* mapping  = (int*)alloc((size_t)N * 4);

  float* scoreF = score2;
  float* scoreL = score2 + N;
  int* sortedF  = sorted2;
  int* sortedL  = sorted2 + N;
  int* rankF    = rank2;
  int* rankL    = rank2 + N;

  float* outF = (float*)d_out;             // [N, D]
  float* outE = outF + (size_t)N * D;      // [2, E]  (fully written by k_edge_zero)
  float* outB = outE + (size_t)2 * E_;     // [N]     (fully written by k_union_map)

  hipMemsetAsync(d_ws, 0, zeroBytes, stream);
  // outF: union rows fully written by the two fuse launches (store / cond-accum);
  // non-union rows zeroed by k_edge_zero -> no 51 MB memset.

  // cluster means + derived (+ twT transpose folded into k_S_SW_HW grid)
  k_hist_cluster<<<(N + 255) / 256, 256, 0, stream>>>(cid, ccount);
  k_scan_small<<<1, 1024, 0, stream>>>(ccount, cstart, C_);
  k_scatter_cluster<<<(N + 255) / 256, 256, 0, stream>>>(cid, cstart, ccur, cslot);
  k_cluster_partial<<<C_ * CSEG, 128, 0, stream>>>(x, cstart, ccount, cslot, Hc);
  k_mean_gdot<<<C_, 128, 0, stream>>>(ccount, wb, Hc, gdot);
  k_S_SW_HW<<<C_ + 1 + D, 128, 0, stream>>>(Hc, tw, SW, HW, twT);

  // fused per-node scores (MLP + GAT projections + minmax partials) + edge softmax
  k_score64<<<NSC64, 256, 0, stream>>>(x, w1, b1, w2, b2, gw, wa, scoreF, hg, aDot, pmmF);
  k_escatter<<<(E_ + 8191) / 8192, 1024, 0, stream>>>(ei, gcnt, payload);
  k_esoftmax<<<NBK, 256, 0, stream>>>(payload, gcnt, hg, gas, gad, gb, scoreL, pmmL);
  k_mm_reduce<<<1, 1024, 0, stream>>>(pmmF, pmmL, mm);

  // exact ranking, both views per launch (minmax folded into producers + 1-block reduce)
  dim3 g2((N + 255) / 256, 2);
  k_bucket_hist2<<<g2, 256, 0, stream>>>(score2, mm, bucket2, hist2);
  k_scan_small<<<2, 1024, 0, stream>>>(hist2, start2, NB);
  k_bucket_scatter2<<<g2, 256, 0, stream>>>(bucket2, start2, cur2, slot2);
  dim3 gr(NB, 2);
  k_bucket_rank3<<<gr, 64, 0, stream>>>(score2, start2, hist2, slot2, rank2, sorted2);

  // union mapping + edge remap + batch + zero non-union rows (merged)
  k_union_chunksum<<<NCHUNK, 1024, 0, stream>>>(rankF, rankL, csums);
  k_scan_small<<<1, 1024, 0, stream>>>(csums, cstarts, NCHUNK);
  k_union_map<<<NCHUNK, 1024, 0, stream>>>(rankF, rankL, cstarts, batch, mapping, outB);
  k_edge_zero<<<EB + ZB, 256, 0, stream>>>(ei, mapping, outE, outF);

  // fused features: launch 1 pure-stores (feat rows); launch 2 stores or
  // accumulates+halves (local rows) depending on feat membership.
  k_fuse64<<<KSEL / 64, 256, 0, stream>>>(x, twT, tb, SW, HW, gdot, aDot, cid, sortedL, sortedF, ab, rankF, outF, 0);
  k_fuse64<<<KSEL / 64, 256, 0, stream>>>(x, twT, tb, SW, HW, gdot, aDot, cid, sortedF, sortedL, ab, rankF, outF, 1);
}

// Round 13
// 520.706 us; speedup vs baseline: 2.7169x; 1.0142x over previous
//
#include <hip/hip_runtime.h>
#include <hip/hip_bf16.h>
#include <stdint.h>

#define N 100000
#define E_ 1600000
#define D 128
#define C_ 256
#define HID 64
#define KSEL 80000
#define NB 4096
#define CHUNK 1024
#define NCHUNK ((N + CHUNK - 1) / CHUNK)   // 98
#define CSEG 32                            // segments per cluster for mean reduction
#define NBK 782                            // ceil(N/128) dst-buckets of 128 nodes
#define BCAP 2560                          // per-bucket capacity (avg 2046 + >11 sigma)
#define RMAX 2048                          // LDS key capacity for in-bucket ranking
#define NSC64 ((N + 63) / 64)              // 1563 score blocks
#define EB ((E_ + 255) / 256)              // 6250 edge blocks
#define ZB ((N * 32 + 255) / 256)          // 12500 zero-row blocks

typedef __attribute__((ext_vector_type(8))) short bf16x8;
typedef __attribute__((ext_vector_type(4))) float f32x4;

// ---- ordered-float encoding (monotonic increasing uint) ----
__device__ __forceinline__ unsigned enc_f(float f) {
  unsigned b = __float_as_uint(f);
  return (b & 0x80000000u) ? ~b : (b | 0x80000000u);
}
__device__ __forceinline__ float dec_f(unsigned u) {
  unsigned b = (u & 0x80000000u) ? (u ^ 0x80000000u) : ~u;
  return __uint_as_float(b);
}

// fp32 -> bf16 round-to-nearest-even (finite inputs)
__device__ __forceinline__ unsigned short f2bf(float f) {
  unsigned u = __float_as_uint(f);
  unsigned r = u + 0x7FFFu + ((u >> 16) & 1u);
  return (unsigned short)(r >> 16);
}

// ======================= cluster CSR + means =======================
__global__ __launch_bounds__(256) void k_hist_cluster(const int* __restrict__ cid, int* __restrict__ ccount) {
  int n = blockIdx.x * 256 + threadIdx.x;
  if (n < N) atomicAdd(&ccount[cid[n]], 1);
}

// generic small scan; block b scans in[b*n .. b*n+n) -> out exclusive
__global__ __launch_bounds__(1024) void k_scan_small(const int* __restrict__ in0, int* __restrict__ out0, int n) {
  __shared__ int sums[1024];
  const int* in = in0 + (size_t)blockIdx.x * n;
  int* out = out0 + (size_t)blockIdx.x * n;
  int t = threadIdx.x;
  int per = (n + 1023) / 1024;
  int base = t * per;
  int loc = 0;
  for (int k = 0; k < per; ++k) { int i = base + k; if (i < n) loc += in[i]; }
  sums[t] = loc; __syncthreads();
  for (int off = 1; off < 1024; off <<= 1) {
    int v = (t >= off) ? sums[t - off] : 0;
    __syncthreads();
    sums[t] += v;
    __syncthreads();
  }
  int run = (t == 0) ? 0 : sums[t - 1];
  for (int k = 0; k < per; ++k) { int i = base + k; if (i < n) { out[i] = run; run += in[i]; } }
}

__global__ __launch_bounds__(256) void k_scatter_cluster(const int* __restrict__ cid, const int* __restrict__ cstart,
                                                         int* __restrict__ ccur, int* __restrict__ cslot) {
  int n = blockIdx.x * 256 + threadIdx.x;
  if (n < N) {
    int c = cid[n];
    int p = cstart[c] + atomicAdd(&ccur[c], 1);
    cslot[p] = n;
  }
}

__global__ __launch_bounds__(128) void k_cluster_partial(const float* __restrict__ x, const int* __restrict__ cstart,
                                                         const int* __restrict__ ccount, const int* __restrict__ cslot,
                                                         float* __restrict__ Hc) {
  int c = blockIdx.x >> 5;
  int s = blockIdx.x & (CSEG - 1);
  int d = threadIdx.x;
  int st = cstart[c], cnt = ccount[c];
  int seg = (cnt + CSEG - 1) / CSEG;
  int lo = s * seg;
  int hi = min(cnt, lo + seg);
  if (lo >= hi) return;
  float acc = 0.f;
  int k = lo;
  for (; k + 2 <= hi; k += 2) {
    int n0 = cslot[st + k], n1 = cslot[st + k + 1];
    float v0 = x[(size_t)n0 * D + d];
    float v1 = x[(size_t)n1 * D + d];
    acc += v0 + v1;
  }
  if (k < hi) acc += x[(size_t)cslot[st + k] * D + d];
  atomicAdd(&Hc[(size_t)c * D + d], acc);
}

// divide Hc by counts, then gdot[c] = Hc[c] . wb  (merged, one launch)
__global__ __launch_bounds__(128) void k_mean_gdot(const int* __restrict__ ccount, const float* __restrict__ wb,
                                                   float* __restrict__ Hc, float* __restrict__ gdot) {
  __shared__ float red[128];
  int c = blockIdx.x, d = threadIdx.x;
  float hv = Hc[(size_t)c * D + d] / (float)max(ccount[c], 1);
  Hc[(size_t)c * D + d] = hv;
  red[d] = hv * wb[d];
  __syncthreads();
  if (d < 64) {
    float v = red[d] + red[d + 64];
    for (int off = 32; off; off >>= 1) v += __shfl_down(v, off);
    if (d == 0) gdot[c] = v;
  }
}

// block 0: S = sum_c Hc[c], SW = S @ tw ; blocks 1..C_: HW[b-1] = Hc[b-1] @ tw ;
// blocks C_+1 .. C_+D: twT row (b-C_-1) = bf16 transpose of tw (folded k_twT).
__global__ __launch_bounds__(128) void k_S_SW_HW(const float* __restrict__ Hc, const float* __restrict__ tw,
                                                 float* __restrict__ SW, float* __restrict__ HW,
                                                 unsigned short* __restrict__ twT) {
  __shared__ float Sl[128];
  int b = blockIdx.x, t = threadIdx.x;
  if (b == 0) {
    float s = 0.f;
    for (int c = 0; c < C_; ++c) s += Hc[(size_t)c * D + t];
    Sl[t] = s;
    __syncthreads();
    float acc = 0.f;
    for (int d = 0; d < D; ++d) acc = fmaf(Sl[d], tw[(size_t)d * D + t], acc);
    SW[t] = acc;
  } else if (b <= C_) {
    const float* src = Hc + (size_t)(b - 1) * D;
    float acc = 0.f;
    for (int d = 0; d < D; ++d) acc = fmaf(src[d], tw[(size_t)d * D + t], acc);
    HW[(size_t)(b - 1) * D + t] = acc;
  } else {
    int k = b - C_ - 1;   // 0..127 ; twT[o][k] = bf16(tw[k][o]), o = t (coalesced read)
    twT[(size_t)t * D + k] = f2bf(tw[(size_t)k * D + t]);
  }
}

// ======== fused per-node scores: MLP (feature view) + GAT h/aDot ========
// fp32 throughout (scoreF drives an exact top-K selection). PROVEN round-6
// configuration (49 us, VGPR 44, zero spill): 256 threads, 4 rows x 4 cols
// per thread, w1 slabs register-prefetched, plain inline LDS reads, pmmF
// plain-store tail. ROUND-7/8 LESSON: do not re-widen to 512 threads.
__global__ __launch_bounds__(256, 4) void k_score64(const float* __restrict__ x, const float* __restrict__ w1,
                                                    const float* __restrict__ b1, const float* __restrict__ w2,
                                                    const float* __restrict__ b2, const float* __restrict__ gw,
                                                    const float* __restrict__ wa, float* __restrict__ scoreF,
                                                    float* __restrict__ hg, float* __restrict__ aDot,
                                                    uint2* __restrict__ pmmF) {
  __shared__ float xld[64 * D];  // 32 KB, swizzled by float4 chunk
  int tid = threadIdx.x;
  int base = blockIdx.x * 64;
#pragma unroll
  for (int k = 0; k < 8; ++k) {
    int i = k * 256 + tid;
    int r = i >> 5, cc = i & 31;
    int n = base + r;
    float4 v = make_float4(0.f, 0.f, 0.f, 0.f);
    if (n < N) v = ((const float4*)(x + (size_t)n * D))[cc];
    ((float4*)xld)[r * 32 + (cc ^ (r & 7))] = v;
  }
  __syncthreads();

  int rg = tid >> 4;        // 16 row-groups of 4 rows
  int cg = tid & 15;        // 16 col-groups of 4 hid cols
  int r0 = rg * 4;
  int c4 = cg * 4;
  float acc[4][4] = {};
  float4 wc0 = *(const float4*)(w1 + (size_t)0 * HID + c4);
  float4 wc1 = *(const float4*)(w1 + (size_t)1 * HID + c4);
  float4 wc2 = *(const float4*)(w1 + (size_t)2 * HID + c4);
  float4 wc3 = *(const float4*)(w1 + (size_t)3 * HID + c4);
  for (int d4 = 0; d4 < D; d4 += 4) {
    float4 wn0, wn1, wn2, wn3;
    if (d4 + 4 < D) {  // prefetch next w1 slab; used only after the 64-FMA block
      wn0 = *(const float4*)(w1 + (size_t)(d4 + 4) * HID + c4);
      wn1 = *(const float4*)(w1 + (size_t)(d4 + 5) * HID + c4);
      wn2 = *(const float4*)(w1 + (size_t)(d4 + 6) * HID + c4);
      wn3 = *(const float4*)(w1 + (size_t)(d4 + 7) * HID + c4);
    } else {
      wn0 = wn1 = wn2 = wn3 = make_float4(0.f, 0.f, 0.f, 0.f);
    }
    int j = d4 >> 2;
#pragma unroll
    for (int rr = 0; rr < 4; ++rr) {
      int row = r0 + rr;
      float4 xv = ((const float4*)xld)[row * 32 + (j ^ (row & 7))];
      acc[rr][0] = fmaf(xv.x, wc0.x, acc[rr][0]);
      acc[rr][1] = fmaf(xv.x, wc0.y, acc[rr][1]);
      acc[rr][2] = fmaf(xv.x, wc0.z, acc[rr][2]);
      acc[rr][3] = fmaf(xv.x, wc0.w, acc[rr][3]);
      acc[rr][0] = fmaf(xv.y, wc1.x, acc[rr][0]);
      acc[rr][1] = fmaf(xv.y, wc1.y, acc[rr][1]);
      acc[rr][2] = fmaf(xv.y, wc1.z, acc[rr][2]);
      acc[rr][3] = fmaf(xv.y, wc1.w, acc[rr][3]);
      acc[rr][0] = fmaf(xv.z, wc2.x, acc[rr][0]);
      acc[rr][1] = fmaf(xv.z, wc2.y, acc[rr][1]);
      acc[rr][2] = fmaf(xv.z, wc2.z, acc[rr][2]);
      acc[rr][3] = fmaf(xv.z, wc2.w, acc[rr][3]);
      acc[rr][0] = fmaf(xv.w, wc3.x, acc[rr][0]);
      acc[rr][1] = fmaf(xv.w, wc3.y, acc[rr][1]);
      acc[rr][2] = fmaf(xv.w, wc3.z, acc[rr][2]);
      acc[rr][3] = fmaf(xv.w, wc3.w, acc[rr][3]);
    }
    wc0 = wn0; wc1 = wn1; wc2 = wn2; wc3 = wn3;
  }

  float4 b1v = *(const float4*)(b1 + c4);
  float4 w2v = *(const float4*)(w2 + c4);
  float bb = b2[0];
  unsigned vmx = 0u, vmn = 0xFFFFFFFFu;
#pragma unroll
  for (int rr = 0; rr < 4; ++rr) {
    float p = fmaxf(acc[rr][0] + b1v.x, 0.f) * w2v.x
            + fmaxf(acc[rr][1] + b1v.y, 0.f) * w2v.y
            + fmaxf(acc[rr][2] + b1v.z, 0.f) * w2v.z
            + fmaxf(acc[rr][3] + b1v.w, 0.f) * w2v.w;
#pragma unroll
    for (int off = 8; off; off >>= 1) p += __shfl_xor(p, off);  // 16-lane group reduce
    if (cg == 0) {
      int n = base + r0 + rr;
      if (n < N) {
        float sf = p + bb;
        scoreF[n] = sf;
        unsigned e = enc_f(sf);
        vmx = max(vmx, e);
        vmn = min(vmn, e);
      }
    }
  }
  // wave-level scoreF min/max (register-only; block combine at the end)
#pragma unroll
  for (int off = 32; off; off >>= 1) {
    vmx = max(vmx, (unsigned)__shfl_xor((int)vmx, off));
    vmn = min(vmn, (unsigned)__shfl_xor((int)vmn, off));
  }

  float4 gwa = *(const float4*)(gw + c4);
  float4 gwb = *(const float4*)(gw + 64 + c4);
  float4 waa = *(const float4*)(wa + c4);
  float4 wab = *(const float4*)(wa + 64 + c4);
#pragma unroll
  for (int rr = 0; rr < 4; ++rr) {
    int row = r0 + rr;
    float4 xa = ((const float4*)xld)[row * 32 + (cg ^ (row & 7))];
    float4 xb = ((const float4*)xld)[row * 32 + ((cg + 16) ^ (row & 7))];
    float hp = xa.x * gwa.x + xa.y * gwa.y + xa.z * gwa.z + xa.w * gwa.w
             + xb.x * gwb.x + xb.y * gwb.y + xb.z * gwb.z + xb.w * gwb.w;
    float ap = xa.x * waa.x + xa.y * waa.y + xa.z * waa.z + xa.w * waa.w
             + xb.x * wab.x + xb.y * wab.y + xb.z * wab.z + xb.w * wab.w;
#pragma unroll
    for (int off = 8; off; off >>= 1) {
      hp += __shfl_xor(hp, off);
      ap += __shfl_xor(ap, off);
    }
    if (cg == 0) {
      int n = base + row;
      if (n < N) { hg[n] = hp; aDot[n] = ap; }
    }
  }

  // block combine through (now-dead) xld; one plain store, no atomics
  __syncthreads();
  if ((tid & 63) == 0) {
    ((unsigned*)xld)[(tid >> 6) * 2] = vmx;
    ((unsigned*)xld)[(tid >> 6) * 2 + 1] = vmn;
  }
  __syncthreads();
  if (tid == 0) {
    const unsigned* xu = (const unsigned*)xld;
    unsigned a = max(max(xu[0], xu[2]), max(xu[4], xu[6]));
    unsigned b = min(min(xu[1], xu[3]), min(xu[5], xu[7]));
    pmmF[blockIdx.x] = make_uint2(a, b);
  }
}

// Bucket edges by dst>>7 with LDS-aggregated reservation. Payload is 4 B/edge
// (s | dl<<24); the GAT logit is recomputed in k_esoftmax.
__global__ __launch_bounds__(1024) void k_escatter(const int* __restrict__ ei, int* __restrict__ gcnt,
                                                   unsigned* __restrict__ payload) {
  __shared__ int lcnt[NBK];
  __shared__ int lbase[NBK];
  int tid = threadIdx.x;
  for (int i = tid; i < NBK; i += 1024) lcnt[i] = 0;
  int e0 = blockIdx.x * 8192;
  int es[8], ed[8];
#pragma unroll
  for (int k = 0; k < 8; ++k) {
    int e = e0 + k * 1024 + tid;
    bool v = (e < E_);
    es[k] = v ? ei[e] : -1;
    ed[k] = v ? ei[E_ + e] : -1;
  }
  __syncthreads();
#pragma unroll
  for (int k = 0; k < 8; ++k)
    if (ed[k] >= 0) atomicAdd(&lcnt[ed[k] >> 7], 1);
  __syncthreads();
  for (int i = tid; i < NBK; i += 1024) {
    int c = lcnt[i];
    lbase[i] = c ? atomicAdd(&gcnt[i], c) : 0;
    lcnt[i] = 0;
  }
  __syncthreads();
#pragma unroll
  for (int k = 0; k < 8; ++k) {
    if (ed[k] < 0) continue;
    int s = es[k], d = ed[k];
    int b = d >> 7, dl = d & 127;
    int pos = lbase[b] + atomicAdd(&lcnt[b], 1);
    if (pos < BCAP) payload[(size_t)b * BCAP + pos] = (unsigned)s | ((unsigned)dl << 24);
  }
}

// Per-bucket GAT softmax in LDS, SINGLE PASS: no segment-max subtraction.
// Mathematically identical (softmax is shift-invariant); overflow-safe since
// |z| <= ~1 for this data (hg sigma~0.57, |a*|<=~0.2 -> exp in [0.4, 2.8]).
// Saves a full payload pass + 1.6M LDS atomicMax vs the 2-pass version.
__global__ __launch_bounds__(256) void k_esoftmax(const unsigned* __restrict__ payload, const int* __restrict__ gcnt,
                                                  const float* __restrict__ hg, const float* __restrict__ asrc,
                                                  const float* __restrict__ adst, const float* __restrict__ gb,
                                                  float* __restrict__ scoreL, uint2* __restrict__ pmmL) {
  __shared__ float dS[128];
  __shared__ float nS[128];
  __shared__ float hgl[128];
  __shared__ unsigned pw[8];
  int b = blockIdx.x;
  int tid = threadIdx.x;
  if (tid < 128) {
    dS[tid] = 0.f; nS[tid] = 0.f;
    int g = b * 128 + tid;
    hgl[tid] = (g < N) ? hg[g] : 0.f;
  }
  __syncthreads();
  float as = asrc[0], ad = adst[0];
  int cnt = min(gcnt[b], BCAP);
  const unsigned* bp = payload + (size_t)b * BCAP;
  for (int i = tid; i < cnt; i += 256) {
    unsigned r = bp[i];
    int s = (int)(r & 0xFFFFFFu), dl = (int)(r >> 24);
    float h = hg[s];
    float z = as * h + ad * hgl[dl];
    float ev = (z > 0.f) ? z : 0.2f * z;
    float ex = expf(ev);
    atomicAdd(&dS[dl], ex);
    atomicAdd(&nS[dl], ex * h);
  }
  __syncthreads();
  unsigned vmx = 0u, vmn = 0xFFFFFFFFu;
  if (tid < 128) {
    int dst = b * 128 + tid;
    if (dst < N) {
      float sl = nS[tid] / fmaxf(dS[tid], 1e-16f) + gb[0];
      scoreL[dst] = sl;
      unsigned e = enc_f(sl);
      vmx = e; vmn = e;
    }
  }
#pragma unroll
  for (int off = 32; off; off >>= 1) {
    vmx = max(vmx, (unsigned)__shfl_xor((int)vmx, off));
    vmn = min(vmn, (unsigned)__shfl_xor((int)vmn, off));
  }
  if ((tid & 63) == 0) { pw[(tid >> 6) * 2] = vmx; pw[(tid >> 6) * 2 + 1] = vmn; }
  __syncthreads();
  if (tid == 0) {
    unsigned a = max(max(pw[0], pw[2]), max(pw[4], pw[6]));
    unsigned c = min(min(pw[1], pw[3]), min(pw[5], pw[7]));
    pmmL[b] = make_uint2(a, c);
  }
}

// single-block reduce of per-block minmax partials -> mm[maxF,maxL,minF,minL]
__global__ __launch_bounds__(1024) void k_mm_reduce(const uint2* __restrict__ pmmF, const uint2* __restrict__ pmmL,
                                                    unsigned* __restrict__ mm) {
  __shared__ unsigned s[4][16];
  int t = threadIdx.x;
  unsigned mxF = 0u, mnF = 0xFFFFFFFFu, mxL = 0u, mnL = 0xFFFFFFFFu;
  for (int i = t; i < NSC64; i += 1024) {
    uint2 v = pmmF[i];
    mxF = max(mxF, v.x); mnF = min(mnF, v.y);
  }
  for (int i = t; i < NBK; i += 1024) {
    uint2 v = pmmL[i];
    mxL = max(mxL, v.x); mnL = min(mnL, v.y);
  }
#pragma unroll
  for (int off = 32; off; off >>= 1) {
    mxF = max(mxF, (unsigned)__shfl_xor((int)mxF, off));
    mnF = min(mnF, (unsigned)__shfl_xor((int)mnF, off));
    mxL = max(mxL, (unsigned)__shfl_xor((int)mxL, off));
    mnL = min(mnL, (unsigned)__shfl_xor((int)mnL, off));
  }
  int w = t >> 6;
  if ((t & 63) == 0) { s[0][w] = mxF; s[1][w] = mnF; s[2][w] = mxL; s[3][w] = mnL; }
  __syncthreads();
  if (t == 0) {
    unsigned a = 0u, b = 0xFFFFFFFFu, c = 0u, d = 0xFFFFFFFFu;
    for (int i = 0; i < 16; ++i) {
      a = max(a, s[0][i]); b = min(b, s[1][i]);
      c = max(c, s[2][i]); d = min(d, s[3][i]);
    }
    mm[0] = a; mm[2] = b; mm[1] = c; mm[3] = d;
  }
}

// ========== exact top-k ranking, both views per launch (blockIdx.y) ==========
__global__ __launch_bounds__(256) void k_bucket_hist2(const float* __restrict__ sc2, const unsigned* __restrict__ mm,
                                                      int* __restrict__ bucket2, int* __restrict__ hist2) {
  int v = blockIdx.y;
  int n = blockIdx.x * 256 + threadIdx.x;
  if (n >= N) return;
  const float* sc = sc2 + (size_t)v * N;
  float smax = dec_f(mm[v]), smin = dec_f(mm[2 + v]);
  float range = smax - smin;
  float scale = (range > 0.f) ? ((float)NB / range) : 0.f;
  float t = (smax - sc[n]) * scale;
  int b = (int)t;
  b = b < 0 ? 0 : (b > NB - 1 ? NB - 1 : b);
  bucket2[(size_t)v * N + n] = b;
  atomicAdd(&hist2[v * NB + b], 1);
}

__global__ __launch_bounds__(256) void k_bucket_scatter2(const int* __restrict__ bucket2, const int* __restrict__ start2,
                                                         int* __restrict__ cur2, int* __restrict__ slot2) {
  int v = blockIdx.y;
  int n = blockIdx.x * 256 + threadIdx.x;
  if (n >= N) return;
  int b = bucket2[(size_t)v * N + n];
  slot2[(size_t)v * N + start2[v * NB + b] + atomicAdd(&cur2[v * NB + b], 1)] = n;
}

// Bucket-centric exact ranking: one wave per bucket, keys staged in LDS once.
__global__ __launch_bounds__(64) void k_bucket_rank3(const float* __restrict__ sc2, const int* __restrict__ start2,
                                                     const int* __restrict__ hist2, const int* __restrict__ slot2,
                                                     int* __restrict__ rank2, int* __restrict__ sorted2) {
  __shared__ unsigned long long keys[RMAX];
  int v = blockIdx.y;
  int b = blockIdx.x;
  int st = start2[v * NB + b], cnt = hist2[v * NB + b];
  if (cnt == 0) return;
  const float* sc = sc2 + (size_t)v * N;
  const int* slot = slot2 + (size_t)v * N;
  int* rank = rank2 + (size_t)v * N;
  int* sorted = sorted2 + (size_t)v * N;
  int tid = threadIdx.x;
  if (cnt <= RMAX) {
    for (int i = tid; i < cnt; i += 64) {
      int m = slot[st + i];
      keys[i] = (((unsigned long long)(~enc_f(sc[m]))) << 32) | (unsigned)m;
    }
    __syncthreads();
    for (int i = tid; i < cnt; i += 64) {
      unsigned long long mykey = keys[i];
      int r = 0;
      for (int j = 0; j < cnt; ++j) r += (keys[j] < mykey) ? 1 : 0;
      int m = (int)(mykey & 0xFFFFFFFFu);
      rank[m] = st + r;
      sorted[st + r] = m;
    }
  } else {  // degenerate-distribution fallback
    for (int i = tid; i < cnt; i += 64) {
      int m = slot[st + i];
      unsigned long long mykey = (((unsigned long long)(~enc_f(sc[m]))) << 32) | (unsigned)m;
      int r = 0;
      for (int j = 0; j < cnt; ++j) {
        int mj = slot[st + j];
        unsigned long long k = (((unsigned long long)(~enc_f(sc[mj]))) << 32) | (unsigned)mj;
        r += (k < mykey) ? 1 : 0;
      }
      rank[m] = st + r;
      sorted[st + r] = m;
    }
  }
}

// ======================= union mapping =======================
__global__ __launch_bounds__(1024) void k_union_chunksum(const int* __restrict__ rankF, const int* __restrict__ rankL,
                                                         int* __restrict__ csum) {
  __shared__ int red[1024];
  int t = threadIdx.x; int i = blockIdx.x * 1024 + t;
  int u = (i < N) ? (((rankF[i] < KSEL) || (rankL[i] < KSEL)) ? 1 : 0) : 0;
  red[t] = u; __syncthreads();
  for (int off = 512; off; off >>= 1) { if (t < off) red[t] += red[t + off]; __syncthreads(); }
  if (t == 0) csum[blockIdx.x] = red[0];
}

__global__ __launch_bounds__(1024) void k_union_map(const int* __restrict__ rankF, const int* __restrict__ rankL,
                                                    const int* __restrict__ cstart, const int* __restrict__ batch,
                                                    int* __restrict__ mapping, float* __restrict__ outBatch) {
  __shared__ int sums[1024];
  int t = threadIdx.x; int i = blockIdx.x * 1024 + t;
  int u = (i < N) ? (((rankF[i] < KSEL) || (rankL[i] < KSEL)) ? 1 : 0) : 0;
  sums[t] = u; __syncthreads();
  for (int off = 1; off < 1024; off <<= 1) {
    int v = (t >= off) ? sums[t - off] : 0;
    __syncthreads();
    sums[t] += v;
    __syncthreads();
  }
  if (i < N) {
    mapping[i] = u ? (cstart[blockIdx.x] + sums[t] - 1) : -1;
    outBatch[i] = u ? (float)batch[i] : -1.0f;
  }
}

// merged: edge remap (blocks [0,EB)) + zero non-union Fp rows (blocks [EB,EB+ZB))
__global__ __launch_bounds__(256) void k_edge_zero(const int* __restrict__ ei, const int* __restrict__ mapping,
                                                   float* __restrict__ outE, float* __restrict__ Fp) {
  int b = blockIdx.x;
  if (b < EB) {
    int e = b * 256 + threadIdx.x;
    if (e >= E_) return;
    int m0 = mapping[ei[e]], m1 = mapping[ei[E_ + e]];
    bool valid = (m0 >= 0) && (m1 >= 0);
    outE[e] = valid ? (float)m0 : -1.f;
    outE[E_ + e] = valid ? (float)m1 : -1.f;
  } else {
    int i = (b - EB) * 256 + threadIdx.x;  // over N*32 float4s
    int n = i >> 5;
    if (n < N && mapping[n] < 0) ((float4*)Fp)[i] = make_float4(0.f, 0.f, 0.f, 0.f);
  }
}

// ======================= fused GCN transform + scatter (MFMA) =======================
// Fp[tgtL[i]] (+)= relu( x[srcL[i]] @ tw + tb + q*SW + (p-q)*HW[cid[srcL[i]]] )
// bf16 MFMA version: compute out^T tiles via D = twT(16o x 32k) . xT(32k x 16n)
// with mfma_f32_16x16x32_bf16. C/D layout (m89-verified): col=lane&15 -> node,
// row=(lane>>4)*4+reg -> 4 consecutive out-channels => coalesced float4 stores.
// x staged in LDS as bf16 [64][128] with XOR swizzle byte^=((row&7)<<4) to break
// the 16-way bank conflict on the stride-256B ds_read_b128 B-frag reads (T2).
// All 4 B-frags preloaded before the MFMA chain (ds_read latency off the
// critical path); twT (bf16, pre-transposed) read straight from global (L1/L2).
__global__ __launch_bounds__(256, 4) void k_fuse64(const float* __restrict__ x, const unsigned short* __restrict__ twT,
                                                   const float* __restrict__ tb, const float* __restrict__ SW,
                                                   const float* __restrict__ HW, const float* __restrict__ gdot,
                                                   const float* __restrict__ aDot, const int* __restrict__ cid,
                                                   const int* __restrict__ srcL, const int* __restrict__ tgtL,
                                                   const float* __restrict__ attb, const int* __restrict__ rankF,
                                                   float* __restrict__ Fp, int accum) {
  __shared__ __align__(16) unsigned xw[64 * 64];  // 64 rows x 128 bf16 cols, 16 KB, swizzled
  __shared__ float pq[64 * 2];
  __shared__ int mt[64 * 2];
  __shared__ int ft[64];
  int tid = threadIdx.x;
  int base = blockIdx.x * 64;
  if (tid < 64) {
    int ws = srcL[base + tid];
    int cc = cid[ws];
    int tg = tgtL[base + tid];
    mt[tid * 2] = cc;
    mt[tid * 2 + 1] = tg;
    ft[tid] = (rankF[tg] < KSEL) ? 1 : 0;
    float s = aDot[ws] + gdot[cc] + attb[0];
    float mx = fmaxf(s, 0.f);
    float esm = expf(s - mx), eom = expf(-mx);
    float dn = esm + 255.f * eom;
    pq[tid * 2] = esm / dn;
    pq[tid * 2 + 1] = eom / dn;
  }
  // stage 64 x-rows as bf16 (2048 float4 loads -> 2048 uint2 LDS writes)
#pragma unroll
  for (int k = 0; k < 8; ++k) {
    int i = k * 256 + tid;
    int r = i >> 5, c4 = i & 31;
    int ws = srcL[base + r];
    float4 v = ((const float4*)(x + (size_t)ws * D))[c4];
    uint2 pk;
    pk.x = (unsigned)f2bf(v.x) | ((unsigned)f2bf(v.y) << 16);
    pk.y = (unsigned)f2bf(v.z) | ((unsigned)f2bf(v.w) << 16);
    int u2 = r * 32 + (c4 ^ ((r & 7) << 1));  // byte = r*256 + ((c4*8) ^ ((r&7)<<4))
    ((uint2*)xw)[u2] = pk;
  }
  __syncthreads();

  int w = tid >> 6;        // wave 0..3 -> node rows w*16 .. w*16+15
  int l = tid & 63;
  int nl = l & 15;         // node within tile (D col)
  int khalf = l >> 4;      // k-block / out-ch subrow selector
  int row = w * 16 + nl;   // LDS x row this lane's B-frags come from

  f32x4 acc[8] = {};       // 8 out-ch tiles of 16 (full 128 out-channels)
  const char* xbase = (const char*)xw + row * 256;
  unsigned rsw = (unsigned)((row & 7) << 4);
  bf16x8 bfr[4];
#pragma unroll
  for (int ks = 0; ks < 4; ++ks)
    bfr[ks] = *(const bf16x8*)(xbase + (((unsigned)(ks * 64 + khalf * 16)) ^ rsw));
#pragma unroll
  for (int ks = 0; ks < 4; ++ks) {
#pragma unroll
    for (int ot = 0; ot < 8; ++ot) {
      // A-frag: twT[ot*16 + nl][ks*32 + khalf*8 .. +7] (16 B from L1/L2)
      bf16x8 afrag = *(const bf16x8*)(twT + (size_t)(ot * 16 + nl) * D + ks * 32 + khalf * 8);
      acc[ot] = __builtin_amdgcn_mfma_f32_16x16x32_bf16(afrag, bfr[ks], acc[ot], 0, 0, 0);
    }
  }

  // epilogue: lane owns node (w*16+nl), channels ot*16 + khalf*4 .. +3
  float p = pq[row * 2], q = pq[row * 2 + 1];
  int cc = mt[row * 2];
  int tgt = mt[row * 2 + 1];
  int doAcc = accum && ft[row];
#pragma unroll
  for (int ot = 0; ot < 8; ++ot) {
    int ch = ot * 16 + khalf * 4;
    float4 tbv = *(const float4*)(tb + ch);
    float4 swv = *(const float4*)(SW + ch);
    float4 hw = *(const float4*)(HW + (size_t)cc * D + ch);
    float4 o;
    o.x = fmaxf(acc[ot][0] + tbv.x + q * swv.x + (p - q) * hw.x, 0.f);
    o.y = fmaxf(acc[ot][1] + tbv.y + q * swv.y + (p - q) * hw.y, 0.f);
    o.z = fmaxf(acc[ot][2] + tbv.z + q * swv.z + (p - q) * hw.z, 0.f);
    o.w = fmaxf(acc[ot][3] + tbv.w + q * swv.w + (p - q) * hw.w, 0.f);
    float4* dst = (float4*)(Fp + (size_t)tgt * D + ch);
    if (doAcc) {
      float4 old = *dst;
      o.x = (o.x + old.x) * 0.5f;
      o.y = (o.y + old.y) * 0.5f;
      o.z = (o.z + old.z) * 0.5f;
      o.w = (o.w + old.w) * 0.5f;
    }
    *dst = o;
  }
}

// ======================= launcher =======================
extern "C" void kernel_launch(void* const* d_in, const int* in_sizes, int n_in,
                              void* d_out, int out_size, void* d_ws, size_t ws_size,
                              hipStream_t stream) {
  const float* x   = (const float*)d_in[0];
  const int* ei    = (const int*)d_in[1];
  const int* batch = (const int*)d_in[2];
  const int* cid   = (const int*)d_in[3];
  const float* w1  = (const float*)d_in[4];
  const float* b1  = (const float*)d_in[5];
  const float* w2  = (const float*)d_in[6];
  const float* b2  = (const float*)d_in[7];
  const float* gw  = (const float*)d_in[8];
  const float* gas = (const float*)d_in[9];
  const float* gad = (const float*)d_in[10];
  const float* gb  = (const float*)d_in[11];
  const float* wa  = (const float*)d_in[12];
  const float* wb  = (const float*)d_in[13];
  const float* ab  = (const float*)d_in[14];
  const float* tw  = (const float*)d_in[15];
  const float* tb  = (const float*)d_in[16];
  (void)in_sizes; (void)n_in; (void)ws_size; (void)out_size;

  char* p = (char*)d_ws;
  auto alloc = [&](size_t bytes) -> char* {
    char* r = p;
    p += (bytes + 255) & ~(size_t)255;
    return r;
  };
  // ---- zero-init region ----
  int* ccount    = (int*)alloc(C_ * 4);
  int* ccur      = (int*)alloc(C_ * 4);
  unsigned* mm   = (unsigned*)alloc(16);                // [maxF,maxL,minF,minL]
  int* hist2     = (int*)alloc(2 * NB * 4);
  int* cur2      = (int*)alloc(2 * NB * 4);
  float* Hc      = (float*)alloc((size_t)C_ * D * 4);   // atomic accumulator
  int* gcnt      = (int*)alloc(NBK * 4);
  size_t zeroBytes = (size_t)(p - (char*)d_ws);
  // ---- rest (fully written before read) ----
  int* cstart   = (int*)alloc(C_ * 4);
  int* cslot    = (int*)alloc((size_t)N * 4);
  float* gdot   = (float*)alloc(C_ * 4);
  float* SW     = (float*)alloc(D * 4);
  float* HW     = (float*)alloc((size_t)C_ * D * 4);
  unsigned short* twT = (unsigned short*)alloc((size_t)D * D * 2);
  float* score2 = (float*)alloc((size_t)2 * N * 4);     // [scoreF | scoreL]
  float* hg     = (float*)alloc((size_t)N * 4);
  float* aDot   = (float*)alloc((size_t)N * 4);
  unsigned* payload = (unsigned*)alloc((size_t)NBK * BCAP * 4);
  uint2* pmmF   = (uint2*)alloc((size_t)NSC64 * 8);
  uint2* pmmL   = (uint2*)alloc((size_t)NBK * 8);
  int* bucket2  = (int*)alloc((size_t)2 * N * 4);
  int* start2   = (int*)alloc(2 * NB * 4);
  int* slot2    = (int*)alloc((size_t)2 * N * 4);
  int* sorted2  = (int*)alloc((size_t)2 * N * 4);
  int* rank2    = (int*)alloc((size_t)2 * N * 4);
  int* csums    = (int*)alloc(NCHUNK * 4);
  int* cstarts  = (int*)alloc(NCHUNK * 4);
  int* mapping  = (int*)alloc((size_t)N * 4);

  float* scoreF = score2;
  float* scoreL = score2 + N;
  int* sortedF  = sorted2;
  int* sortedL  = sorted2 + N;
  int* rankF    = rank2;
  int* rankL    = rank2 + N;

  float* outF = (float*)d_out;             // [N, D]
  float* outE = outF + (size_t)N * D;      // [2, E]  (fully written by k_edge_zero)
  float* outB = outE + (size_t)2 * E_;     // [N]     (fully written by k_union_map)

  hipMemsetAsync(d_ws, 0, zeroBytes, stream);
  // outF: union rows fully written by the two fuse launches (store / cond-accum);
  // non-union rows zeroed by k_edge_zero -> no 51 MB memset.

  // cluster means + derived (+ twT transpose folded into k_S_SW_HW grid)
  k_hist_cluster<<<(N + 255) / 256, 256, 0, stream>>>(cid, ccount);
  k_scan_small<<<1, 1024, 0, stream>>>(ccount, cstart, C_);
  k_scatter_cluster<<<(N + 255) / 256, 256, 0, stream>>>(cid, cstart, ccur, cslot);
  k_cluster_partial<<<C_ * CSEG, 128, 0, stream>>>(x, cstart, ccount, cslot, Hc);
  k_mean_gdot<<<C_, 128, 0, stream>>>(ccount, wb, Hc, gdot);
  k_S_SW_HW<<<C_ + 1 + D, 128, 0, stream>>>(Hc, tw, SW, HW, twT);

  // fused per-node scores (MLP + GAT projections + minmax partials) + edge softmax
  k_score64<<<NSC64, 256, 0, stream>>>(x, w1, b1, w2, b2, gw, wa, scoreF, hg, aDot, pmmF);
  k_escatter<<<(E_ + 8191) / 8192, 1024, 0, stream>>>(ei, gcnt, payload);
  k_esoftmax<<<NBK, 256, 0, stream>>>(payload, gcnt, hg, gas, gad, gb, scoreL, pmmL);
  k_mm_reduce<<<1, 1024, 0, stream>>>(pmmF, pmmL, mm);

  // exact ranking, both views per launch (minmax folded into producers + 1-block reduce)
  dim3 g2((N + 255) / 256, 2);
  k_bucket_hist2<<<g2, 256, 0, stream>>>(score2, mm, bucket2, hist2);
  k_scan_small<<<2, 1024, 0, stream>>>(hist2, start2, NB);
  k_bucket_scatter2<<<g2, 256, 0, stream>>>(bucket2, start2, cur2, slot2);
  dim3 gr(NB, 2);
  k_bucket_rank3<<<gr, 64, 0, stream>>>(score2, start2, hist2, slot2, rank2, sorted2);

  // union mapping + edge remap + batch + zero non-union rows (merged)
  k_union_chunksum<<<NCHUNK, 1024, 0, stream>>>(rankF, rankL, csums);
  k_scan_small<<<1, 1024, 0, stream>>>(csums, cstarts, NCHUNK);
  k_union_map<<<NCHUNK, 1024, 0, stream>>>(rankF, rankL, cstarts, batch, mapping, outB);
  k_edge_zero<<<EB + ZB, 256, 0, stream>>>(ei, mapping, outE, outF);

  // fused features: launch 1 pure-stores (feat rows); launch 2 stores or
  // accumulates+halves (local rows) depending on feat membership.
  k_fuse64<<<KSEL / 64, 256, 0, stream>>>(x, twT, tb, SW, HW, gdot, aDot, cid, sortedL, sortedF, ab, rankF, outF, 0);
  k_fuse64<<<KSEL / 64, 256, 0, stream>>>(x, twT, tb, SW, HW, gdot, aDot, cid, sortedF, sortedL, ab, rankF, outF, 1);
}

// Round 16
// 495.228 us; speedup vs baseline: 2.8567x; 1.0514x over previous
//
#include <hip/hip_runtime.h>
#include <hip/hip_bf16.h>
#include <stdint.h>

#define N 100000
#define E_ 1600000
#define D 128
#define C_ 256
#define HID 64
#define KSEL 80000
#define NB 4096
#define CHUNK 1024
#define NCHUNK ((N + CHUNK - 1) / CHUNK)   // 98
#define CSEG 32                            // segments per cluster for mean reduction
#define NBK 782                            // ceil(N/128) dst-buckets of 128 nodes
#define BCAP 2560                          // per-bucket capacity (avg 2046 + >11 sigma)
#define RMAX 2048                          // LDS key capacity for in-bucket ranking
#define NSC64 ((N + 63) / 64)              // 1563 score blocks
#define EB ((E_ + 255) / 256)              // 6250 edge blocks
#define ZB ((N * 32 + 255) / 256)          // 12500 zero-row blocks

typedef __attribute__((ext_vector_type(8))) short bf16x8;
typedef __attribute__((ext_vector_type(4))) float f32x4;

// ---- ordered-float encoding (monotonic increasing uint) ----
__device__ __forceinline__ unsigned enc_f(float f) {
  unsigned b = __float_as_uint(f);
  return (b & 0x80000000u) ? ~b : (b | 0x80000000u);
}
__device__ __forceinline__ float dec_f(unsigned u) {
  unsigned b = (u & 0x80000000u) ? (u ^ 0x80000000u) : ~u;
  return __uint_as_float(b);
}

// fp32 -> bf16 round-to-nearest-even (finite inputs)
__device__ __forceinline__ unsigned short f2bf(float f) {
  unsigned u = __float_as_uint(f);
  unsigned r = u + 0x7FFFu + ((u >> 16) & 1u);
  return (unsigned short)(r >> 16);
}

// ======================= cluster CSR + means =======================
__global__ __launch_bounds__(256) void k_hist_cluster(const int* __restrict__ cid, int* __restrict__ ccount) {
  int n = blockIdx.x * 256 + threadIdx.x;
  if (n < N) atomicAdd(&ccount[cid[n]], 1);
}

// generic small scan; block b scans in[b*n .. b*n+n) -> out exclusive
__global__ __launch_bounds__(1024) void k_scan_small(const int* __restrict__ in0, int* __restrict__ out0, int n) {
  __shared__ int sums[1024];
  const int* in = in0 + (size_t)blockIdx.x * n;
  int* out = out0 + (size_t)blockIdx.x * n;
  int t = threadIdx.x;
  int per = (n + 1023) / 1024;
  int base = t * per;
  int loc = 0;
  for (int k = 0; k < per; ++k) { int i = base + k; if (i < n) loc += in[i]; }
  sums[t] = loc; __syncthreads();
  for (int off = 1; off < 1024; off <<= 1) {
    int v = (t >= off) ? sums[t - off] : 0;
    __syncthreads();
    sums[t] += v;
    __syncthreads();
  }
  int run = (t == 0) ? 0 : sums[t - 1];
  for (int k = 0; k < per; ++k) { int i = base + k; if (i < n) { out[i] = run; run += in[i]; } }
}

__global__ __launch_bounds__(256) void k_scatter_cluster(const int* __restrict__ cid, const int* __restrict__ cstart,
                                                         int* __restrict__ ccur, int* __restrict__ cslot) {
  int n = blockIdx.x * 256 + threadIdx.x;
  if (n < N) {
    int c = cid[n];
    int p = cstart[c] + atomicAdd(&ccur[c], 1);
    cslot[p] = n;
  }
}

__global__ __launch_bounds__(128) void k_cluster_partial(const float* __restrict__ x, const int* __restrict__ cstart,
                                                         const int* __restrict__ ccount, const int* __restrict__ cslot,
                                                         float* __restrict__ Hc) {
  int c = blockIdx.x >> 5;
  int s = blockIdx.x & (CSEG - 1);
  int d = threadIdx.x;
  int st = cstart[c], cnt = ccount[c];
  int seg = (cnt + CSEG - 1) / CSEG;
  int lo = s * seg;
  int hi = min(cnt, lo + seg);
  if (lo >= hi) return;
  float acc = 0.f;
  int k = lo;
  for (; k + 2 <= hi; k += 2) {
    int n0 = cslot[st + k], n1 = cslot[st + k + 1];
    float v0 = x[(size_t)n0 * D + d];
    float v1 = x[(size_t)n1 * D + d];
    acc += v0 + v1;
  }
  if (k < hi) acc += x[(size_t)cslot[st + k] * D + d];
  atomicAdd(&Hc[(size_t)c * D + d], acc);
}

// divide Hc by counts, then gdot[c] = Hc[c] . wb  (merged, one launch)
__global__ __launch_bounds__(128) void k_mean_gdot(const int* __restrict__ ccount, const float* __restrict__ wb,
                                                   float* __restrict__ Hc, float* __restrict__ gdot) {
  __shared__ float red[128];
  int c = blockIdx.x, d = threadIdx.x;
  float hv = Hc[(size_t)c * D + d] / (float)max(ccount[c], 1);
  Hc[(size_t)c * D + d] = hv;
  red[d] = hv * wb[d];
  __syncthreads();
  if (d < 64) {
    float v = red[d] + red[d + 64];
    for (int off = 32; off; off >>= 1) v += __shfl_down(v, off);
    if (d == 0) gdot[c] = v;
  }
}

// block 0: S = sum_c Hc[c], SW = S @ tw ; blocks 1..C_: HW[b-1] = Hc[b-1] @ tw ;
// blocks C_+1 .. C_+D: twT row (b-C_-1) = bf16 transpose of tw (folded k_twT).
__global__ __launch_bounds__(128) void k_S_SW_HW(const float* __restrict__ Hc, const float* __restrict__ tw,
                                                 float* __restrict__ SW, float* __restrict__ HW,
                                                 unsigned short* __restrict__ twT) {
  __shared__ float Sl[128];
  int b = blockIdx.x, t = threadIdx.x;
  if (b == 0) {
    float s = 0.f;
    for (int c = 0; c < C_; ++c) s += Hc[(size_t)c * D + t];
    Sl[t] = s;
    __syncthreads();
    float acc = 0.f;
    for (int d = 0; d < D; ++d) acc = fmaf(Sl[d], tw[(size_t)d * D + t], acc);
    SW[t] = acc;
  } else if (b <= C_) {
    const float* src = Hc + (size_t)(b - 1) * D;
    float acc = 0.f;
    for (int d = 0; d < D; ++d) acc = fmaf(src[d], tw[(size_t)d * D + t], acc);
    HW[(size_t)(b - 1) * D + t] = acc;
  } else {
    int k = b - C_ - 1;   // 0..127 ; twT[o][k] = bf16(tw[k][o]), o = t (coalesced read)
    twT[(size_t)t * D + k] = f2bf(tw[(size_t)k * D + t]);
  }
}

// ======== fused per-node scores: MLP (feature view) + GAT h/aDot ========
// fp32 throughout (scoreF drives an exact top-K selection). PROVEN round-6
// configuration (49 us, VGPR 44, zero spill): 256 threads, 4 rows x 4 cols
// per thread, w1 slabs register-prefetched, plain inline LDS reads, pmmF
// plain-store tail. ROUND-7/8 LESSON: do not re-widen to 512 threads.
__global__ __launch_bounds__(256, 4) void k_score64(const float* __restrict__ x, const float* __restrict__ w1,
                                                    const float* __restrict__ b1, const float* __restrict__ w2,
                                                    const float* __restrict__ b2, const float* __restrict__ gw,
                                                    const float* __restrict__ wa, float* __restrict__ scoreF,
                                                    float* __restrict__ hg, float* __restrict__ aDot,
                                                    uint2* __restrict__ pmmF) {
  __shared__ float xld[64 * D];  // 32 KB, swizzled by float4 chunk
  int tid = threadIdx.x;
  int base = blockIdx.x * 64;
#pragma unroll
  for (int k = 0; k < 8; ++k) {
    int i = k * 256 + tid;
    int r = i >> 5, cc = i & 31;
    int n = base + r;
    float4 v = make_float4(0.f, 0.f, 0.f, 0.f);
    if (n < N) v = ((const float4*)(x + (size_t)n * D))[cc];
    ((float4*)xld)[r * 32 + (cc ^ (r & 7))] = v;
  }
  __syncthreads();

  int rg = tid >> 4;        // 16 row-groups of 4 rows
  int cg = tid & 15;        // 16 col-groups of 4 hid cols
  int r0 = rg * 4;
  int c4 = cg * 4;
  float acc[4][4] = {};
  float4 wc0 = *(const float4*)(w1 + (size_t)0 * HID + c4);
  float4 wc1 = *(const float4*)(w1 + (size_t)1 * HID + c4);
  float4 wc2 = *(const float4*)(w1 + (size_t)2 * HID + c4);
  float4 wc3 = *(const float4*)(w1 + (size_t)3 * HID + c4);
  for (int d4 = 0; d4 < D; d4 += 4) {
    float4 wn0, wn1, wn2, wn3;
    if (d4 + 4 < D) {  // prefetch next w1 slab; used only after the 64-FMA block
      wn0 = *(const float4*)(w1 + (size_t)(d4 + 4) * HID + c4);
      wn1 = *(const float4*)(w1 + (size_t)(d4 + 5) * HID + c4);
      wn2 = *(const float4*)(w1 + (size_t)(d4 + 6) * HID + c4);
      wn3 = *(const float4*)(w1 + (size_t)(d4 + 7) * HID + c4);
    } else {
      wn0 = wn1 = wn2 = wn3 = make_float4(0.f, 0.f, 0.f, 0.f);
    }
    int j = d4 >> 2;
#pragma unroll
    for (int rr = 0; rr < 4; ++rr) {
      int row = r0 + rr;
      float4 xv = ((const float4*)xld)[row * 32 + (j ^ (row & 7))];
      acc[rr][0] = fmaf(xv.x, wc0.x, acc[rr][0]);
      acc[rr][1] = fmaf(xv.x, wc0.y, acc[rr][1]);
      acc[rr][2] = fmaf(xv.x, wc0.z, acc[rr][2]);
      acc[rr][3] = fmaf(xv.x, wc0.w, acc[rr][3]);
      acc[rr][0] = fmaf(xv.y, wc1.x, acc[rr][0]);
      acc[rr][1] = fmaf(xv.y, wc1.y, acc[rr][1]);
      acc[rr][2] = fmaf(xv.y, wc1.z, acc[rr][2]);
      acc[rr][3] = fmaf(xv.y, wc1.w, acc[rr][3]);
      acc[rr][0] = fmaf(xv.z, wc2.x, acc[rr][0]);
      acc[rr][1] = fmaf(xv.z, wc2.y, acc[rr][1]);
      acc[rr][2] = fmaf(xv.z, wc2.z, acc[rr][2]);
      acc[rr][3] = fmaf(xv.z, wc2.w, acc[rr][3]);
      acc[rr][0] = fmaf(xv.w, wc3.x, acc[rr][0]);
      acc[rr][1] = fmaf(xv.w, wc3.y, acc[rr][1]);
      acc[rr][2] = fmaf(xv.w, wc3.z, acc[rr][2]);
      acc[rr][3] = fmaf(xv.w, wc3.w, acc[rr][3]);
    }
    wc0 = wn0; wc1 = wn1; wc2 = wn2; wc3 = wn3;
  }

  float4 b1v = *(const float4*)(b1 + c4);
  float4 w2v = *(const float4*)(w2 + c4);
  float bb = b2[0];
  unsigned vmx = 0u, vmn = 0xFFFFFFFFu;
#pragma unroll
  for (int rr = 0; rr < 4; ++rr) {
    float p = fmaxf(acc[rr][0] + b1v.x, 0.f) * w2v.x
            + fmaxf(acc[rr][1] + b1v.y, 0.f) * w2v.y
            + fmaxf(acc[rr][2] + b1v.z, 0.f) * w2v.z
            + fmaxf(acc[rr][3] + b1v.w, 0.f) * w2v.w;
#pragma unroll
    for (int off = 8; off; off >>= 1) p += __shfl_xor(p, off);  // 16-lane group reduce
    if (cg == 0) {
      int n = base + r0 + rr;
      if (n < N) {
        float sf = p + bb;
        scoreF[n] = sf;
        unsigned e = enc_f(sf);
        vmx = max(vmx, e);
        vmn = min(vmn, e);
      }
    }
  }
  // wave-level scoreF min/max (register-only; block combine at the end)
#pragma unroll
  for (int off = 32; off; off >>= 1) {
    vmx = max(vmx, (unsigned)__shfl_xor((int)vmx, off));
    vmn = min(vmn, (unsigned)__shfl_xor((int)vmn, off));
  }

  float4 gwa = *(const float4*)(gw + c4);
  float4 gwb = *(const float4*)(gw + 64 + c4);
  float4 waa = *(const float4*)(wa + c4);
  float4 wab = *(const float4*)(wa + 64 + c4);
#pragma unroll
  for (int rr = 0; rr < 4; ++rr) {
    int row = r0 + rr;
    float4 xa = ((const float4*)xld)[row * 32 + (cg ^ (row & 7))];
    float4 xb = ((const float4*)xld)[row * 32 + ((cg + 16) ^ (row & 7))];
    float hp = xa.x * gwa.x + xa.y * gwa.y + xa.z * gwa.z + xa.w * gwa.w
             + xb.x * gwb.x + xb.y * gwb.y + xb.z * gwb.z + xb.w * gwb.w;
    float ap = xa.x * waa.x + xa.y * waa.y + xa.z * waa.z + xa.w * waa.w
             + xb.x * wab.x + xb.y * wab.y + xb.z * wab.z + xb.w * wab.w;
#pragma unroll
    for (int off = 8; off; off >>= 1) {
      hp += __shfl_xor(hp, off);
      ap += __shfl_xor(ap, off);
    }
    if (cg == 0) {
      int n = base + row;
      if (n < N) { hg[n] = hp; aDot[n] = ap; }
    }
  }

  // block combine through (now-dead) xld; one plain store, no atomics
  __syncthreads();
  if ((tid & 63) == 0) {
    ((unsigned*)xld)[(tid >> 6) * 2] = vmx;
    ((unsigned*)xld)[(tid >> 6) * 2 + 1] = vmn;
  }
  __syncthreads();
  if (tid == 0) {
    const unsigned* xu = (const unsigned*)xld;
    unsigned a = max(max(xu[0], xu[2]), max(xu[4], xu[6]));
    unsigned b = min(min(xu[1], xu[3]), min(xu[5], xu[7]));
    pmmF[blockIdx.x] = make_uint2(a, b);
  }
}

// Bucket edges by dst>>7 with LDS-aggregated reservation. Payload is 4 B/edge
// (s | dl<<24); the GAT logit is recomputed in k_esoftmax.
__global__ __launch_bounds__(1024) void k_escatter(const int* __restrict__ ei, int* __restrict__ gcnt,
                                                   unsigned* __restrict__ payload) {
  __shared__ int lcnt[NBK];
  __shared__ int lbase[NBK];
  int tid = threadIdx.x;
  for (int i = tid; i < NBK; i += 1024) lcnt[i] = 0;
  int e0 = blockIdx.x * 8192;
  int es[8], ed[8];
#pragma unroll
  for (int k = 0; k < 8; ++k) {
    int e = e0 + k * 1024 + tid;
    bool v = (e < E_);
    es[k] = v ? ei[e] : -1;
    ed[k] = v ? ei[E_ + e] : -1;
  }
  __syncthreads();
#pragma unroll
  for (int k = 0; k < 8; ++k)
    if (ed[k] >= 0) atomicAdd(&lcnt[ed[k] >> 7], 1);
  __syncthreads();
  for (int i = tid; i < NBK; i += 1024) {
    int c = lcnt[i];
    lbase[i] = c ? atomicAdd(&gcnt[i], c) : 0;
    lcnt[i] = 0;
  }
  __syncthreads();
#pragma unroll
  for (int k = 0; k < 8; ++k) {
    if (ed[k] < 0) continue;
    int s = es[k], d = ed[k];
    int b = d >> 7, dl = d & 127;
    int pos = lbase[b] + atomicAdd(&lcnt[b], 1);
    if (pos < BCAP) payload[(size_t)b * BCAP + pos] = (unsigned)s | ((unsigned)dl << 24);
  }
}

// Per-bucket GAT softmax in LDS, SINGLE PASS: no segment-max subtraction.
// Mathematically identical (softmax is shift-invariant); overflow-safe since
// |z| <= ~1 for this data (hg sigma~0.57, |a*|<=~0.2 -> exp in [0.4, 2.8]).
// Saves a full payload pass + 1.6M LDS atomicMax vs the 2-pass version.
__global__ __launch_bounds__(256) void k_esoftmax(const unsigned* __restrict__ payload, const int* __restrict__ gcnt,
                                                  const float* __restrict__ hg, const float* __restrict__ asrc,
                                                  const float* __restrict__ adst, const float* __restrict__ gb,
                                                  float* __restrict__ scoreL, uint2* __restrict__ pmmL) {
  __shared__ float dS[128];
  __shared__ float nS[128];
  __shared__ float hgl[128];
  __shared__ unsigned pw[8];
  int b = blockIdx.x;
  int tid = threadIdx.x;
  if (tid < 128) {
    dS[tid] = 0.f; nS[tid] = 0.f;
    int g = b * 128 + tid;
    hgl[tid] = (g < N) ? hg[g] : 0.f;
  }
  __syncthreads();
  float as = asrc[0], ad = adst[0];
  int cnt = min(gcnt[b], BCAP);
  const unsigned* bp = payload + (size_t)b * BCAP;
  for (int i = tid; i < cnt; i += 256) {
    unsigned r = bp[i];
    int s = (int)(r & 0xFFFFFFu), dl = (int)(r >> 24);
    float h = hg[s];
    float z = as * h + ad * hgl[dl];
    float ev = (z > 0.f) ? z : 0.2f * z;
    float ex = expf(ev);
    atomicAdd(&dS[dl], ex);
    atomicAdd(&nS[dl], ex * h);
  }
  __syncthreads();
  unsigned vmx = 0u, vmn = 0xFFFFFFFFu;
  if (tid < 128) {
    int dst = b * 128 + tid;
    if (dst < N) {
      float sl = nS[tid] / fmaxf(dS[tid], 1e-16f) + gb[0];
      scoreL[dst] = sl;
      unsigned e = enc_f(sl);
      vmx = e; vmn = e;
    }
  }
#pragma unroll
  for (int off = 32; off; off >>= 1) {
    vmx = max(vmx, (unsigned)__shfl_xor((int)vmx, off));
    vmn = min(vmn, (unsigned)__shfl_xor((int)vmn, off));
  }
  if ((tid & 63) == 0) { pw[(tid >> 6) * 2] = vmx; pw[(tid >> 6) * 2 + 1] = vmn; }
  __syncthreads();
  if (tid == 0) {
    unsigned a = max(max(pw[0], pw[2]), max(pw[4], pw[6]));
    unsigned c = min(min(pw[1], pw[3]), min(pw[5], pw[7]));
    pmmL[b] = make_uint2(a, c);
  }
}

// single-block reduce of per-block minmax partials -> mm[maxF,maxL,minF,minL]
__global__ __launch_bounds__(1024) void k_mm_reduce(const uint2* __restrict__ pmmF, const uint2* __restrict__ pmmL,
                                                    unsigned* __restrict__ mm) {
  __shared__ unsigned s[4][16];
  int t = threadIdx.x;
  unsigned mxF = 0u, mnF = 0xFFFFFFFFu, mxL = 0u, mnL = 0xFFFFFFFFu;
  for (int i = t; i < NSC64; i += 1024) {
    uint2 v = pmmF[i];
    mxF = max(mxF, v.x); mnF = min(mnF, v.y);
  }
  for (int i = t; i < NBK; i += 1024) {
    uint2 v = pmmL[i];
    mxL = max(mxL, v.x); mnL = min(mnL, v.y);
  }
#pragma unroll
  for (int off = 32; off; off >>= 1) {
    mxF = max(mxF, (unsigned)__shfl_xor((int)mxF, off));
    mnF = min(mnF, (unsigned)__shfl_xor((int)mnF, off));
    mxL = max(mxL, (unsigned)__shfl_xor((int)mxL, off));
    mnL = min(mnL, (unsigned)__shfl_xor((int)mnL, off));
  }
  int w = t >> 6;
  if ((t & 63) == 0) { s[0][w] = mxF; s[1][w] = mnF; s[2][w] = mxL; s[3][w] = mnL; }
  __syncthreads();
  if (t == 0) {
    unsigned a = 0u, b = 0xFFFFFFFFu, c = 0u, d = 0xFFFFFFFFu;
    for (int i = 0; i < 16; ++i) {
      a = max(a, s[0][i]); b = min(b, s[1][i]);
      c = max(c, s[2][i]); d = min(d, s[3][i]);
    }
    mm[0] = a; mm[2] = b; mm[1] = c; mm[3] = d;
  }
}

// ========== exact top-k ranking, both views per launch (blockIdx.y) ==========
__global__ __launch_bounds__(256) void k_bucket_hist2(const float* __restrict__ sc2, const unsigned* __restrict__ mm,
                                                      int* __restrict__ bucket2, int* __restrict__ hist2) {
  int v = blockIdx.y;
  int n = blockIdx.x * 256 + threadIdx.x;
  if (n >= N) return;
  const float* sc = sc2 + (size_t)v * N;
  float smax = dec_f(mm[v]), smin = dec_f(mm[2 + v]);
  float range = smax - smin;
  float scale = (range > 0.f) ? ((float)NB / range) : 0.f;
  float t = (smax - sc[n]) * scale;
  int b = (int)t;
  b = b < 0 ? 0 : (b > NB - 1 ? NB - 1 : b);
  bucket2[(size_t)v * N + n] = b;
  atomicAdd(&hist2[v * NB + b], 1);
}

__global__ __launch_bounds__(256) void k_bucket_scatter2(const int* __restrict__ bucket2, const int* __restrict__ start2,
                                                         int* __restrict__ cur2, int* __restrict__ slot2) {
  int v = blockIdx.y;
  int n = blockIdx.x * 256 + threadIdx.x;
  if (n >= N) return;
  int b = bucket2[(size_t)v * N + n];
  slot2[(size_t)v * N + start2[v * NB + b] + atomicAdd(&cur2[v * NB + b], 1)] = n;
}

// Bucket-centric exact ranking: one wave per bucket, keys staged in LDS once.
__global__ __launch_bounds__(64) void k_bucket_rank3(const float* __restrict__ sc2, const int* __restrict__ start2,
                                                     const int* __restrict__ hist2, const int* __restrict__ slot2,
                                                     int* __restrict__ rank2, int* __restrict__ sorted2) {
  __shared__ unsigned long long keys[RMAX];
  int v = blockIdx.y;
  int b = blockIdx.x;
  int st = start2[v * NB + b], cnt = hist2[v * NB + b];
  if (cnt == 0) return;
  const float* sc = sc2 + (size_t)v * N;
  const int* slot = slot2 + (size_t)v * N;
  int* rank = rank2 + (size_t)v * N;
  int* sorted = sorted2 + (size_t)v * N;
  int tid = threadIdx.x;
  if (cnt <= RMAX) {
    for (int i = tid; i < cnt; i += 64) {
      int m = slot[st + i];
      keys[i] = (((unsigned long long)(~enc_f(sc[m]))) << 32) | (unsigned)m;
    }
    __syncthreads();
    for (int i = tid; i < cnt; i += 64) {
      unsigned long long mykey = keys[i];
      int r = 0;
      for (int j = 0; j < cnt; ++j) r += (keys[j] < mykey) ? 1 : 0;
      int m = (int)(mykey & 0xFFFFFFFFu);
      rank[m] = st + r;
      sorted[st + r] = m;
    }
  } else {  // degenerate-distribution fallback
    for (int i = tid; i < cnt; i += 64) {
      int m = slot[st + i];
      unsigned long long mykey = (((unsigned long long)(~enc_f(sc[m]))) << 32) | (unsigned)m;
      int r = 0;
      for (int j = 0; j < cnt; ++j) {
        int mj = slot[st + j];
        unsigned long long k = (((unsigned long long)(~enc_f(sc[mj]))) << 32) | (unsigned)mj;
        r += (k < mykey) ? 1 : 0;
      }
      rank[m] = st + r;
      sorted[st + r] = m;
    }
  }
}

// ======================= union mapping =======================
__global__ __launch_bounds__(1024) void k_union_chunksum(const int* __restrict__ rankF, const int* __restrict__ rankL,
                                                         int* __restrict__ csum) {
  __shared__ int red[1024];
  int t = threadIdx.x; int i = blockIdx.x * 1024 + t;
  int u = (i < N) ? (((rankF[i] < KSEL) || (rankL[i] < KSEL)) ? 1 : 0) : 0;
  red[t] = u; __syncthreads();
  for (int off = 512; off; off >>= 1) { if (t < off) red[t] += red[t + off]; __syncthreads(); }
  if (t == 0) csum[blockIdx.x] = red[0];
}

// also emits ulist: ulist[mapping[i]] = i (ascending union node list for k_fuseU)
__global__ __launch_bounds__(1024) void k_union_map(const int* __restrict__ rankF, const int* __restrict__ rankL,
                                                    const int* __restrict__ cstart, const int* __restrict__ batch,
                                                    int* __restrict__ mapping, float* __restrict__ outBatch,
                                                    int* __restrict__ ulist) {
  __shared__ int sums[1024];
  int t = threadIdx.x; int i = blockIdx.x * 1024 + t;
  int u = (i < N) ? (((rankF[i] < KSEL) || (rankL[i] < KSEL)) ? 1 : 0) : 0;
  sums[t] = u; __syncthreads();
  for (int off = 1; off < 1024; off <<= 1) {
    int v = (t >= off) ? sums[t - off] : 0;
    __syncthreads();
    sums[t] += v;
    __syncthreads();
  }
  if (i < N) {
    int m_ = u ? (cstart[blockIdx.x] + sums[t] - 1) : -1;
    mapping[i] = m_;
    if (u) ulist[m_] = i;
    outBatch[i] = u ? (float)batch[i] : -1.0f;
  }
}

// merged: edge remap (blocks [0,EB)) + zero non-union Fp rows (blocks [EB,EB+ZB))
__global__ __launch_bounds__(256) void k_edge_zero(const int* __restrict__ ei, const int* __restrict__ mapping,
                                                   float* __restrict__ outE, float* __restrict__ Fp) {
  int b = blockIdx.x;
  if (b < EB) {
    int e = b * 256 + threadIdx.x;
    if (e >= E_) return;
    int m0 = mapping[ei[e]], m1 = mapping[ei[E_ + e]];
    bool valid = (m0 >= 0) && (m1 >= 0);
    outE[e] = valid ? (float)m0 : -1.f;
    outE[E_ + e] = valid ? (float)m1 : -1.f;
  } else {
    int i = (b - EB) * 256 + threadIdx.x;  // over N*32 float4s
    int n = i >> 5;
    if (n < N && mapping[n] < 0) ((float4*)Fp)[i] = make_float4(0.f, 0.f, 0.f, 0.f);
  }
}

// ============ merged target-centric fused GCN transform (MFMA) ============
// One launch over the union list (ascending node ids -> near-sequential
// writes). For union row t:
//   A = relu(x[sortedL[rankF[t]]]@tw + tb + qA*SW + (pA-qA)*HW[cidA])  if rankF[t]<K
//   B = relu(x[sortedF[rankL[t]]]@tw + tb + qB*SW + (pB-qB)*HW[cidB])  if rankL[t]<K
//   Fp[t] = both ? (A+B)*0.5 : (A or B)     -- bit-identical to the old
// store-then-RMW two-launch pair (same fp32 operands, addition commutes).
// Eliminates ~33 MB Fp read-back + ~33 MB duplicate writes + 1 launch.
// A-fragments (twT) are shared between the A and B MFMA chains.
// NOTE: plain launch_bounds(256) -- no min-occupancy arg (round-7/8 spill trap);
// ~16 f32x4 accumulators need VGPR headroom.
__global__ __launch_bounds__(256) void k_fuseU(const float* __restrict__ x, const unsigned short* __restrict__ twT,
                                               const float* __restrict__ tb, const float* __restrict__ SW,
                                               const float* __restrict__ HW, const float* __restrict__ gdot,
                                               const float* __restrict__ aDot, const int* __restrict__ cid,
                                               const int* __restrict__ sortedF, const int* __restrict__ sortedL,
                                               const int* __restrict__ rankF, const int* __restrict__ rankL,
                                               const int* __restrict__ ulist, const int* __restrict__ cstarts,
                                               const int* __restrict__ csums, const float* __restrict__ attb,
                                               float* __restrict__ Fp) {
  __shared__ __align__(16) unsigned xwA[64 * 64];  // 16 KB bf16, swizzled
  __shared__ __align__(16) unsigned xwB[64 * 64];  // 16 KB
  __shared__ float pqA[64 * 2], pqB[64 * 2];
  __shared__ int mtA[64], mtB[64];   // cid of srcA / srcB
  __shared__ int tgl[64];            // target node (-1 = inactive row)
  __shared__ int fl[64];             // bit0 = A valid, bit1 = B valid
  __shared__ int srcAB[64 * 2];
  int tid = threadIdx.x;
  int base = blockIdx.x * 64;
  int UC = cstarts[NCHUNK - 1] + csums[NCHUNK - 1];
  if (base >= UC) return;
  if (tid < 64) {
    int pos = base + tid;
    int t = (pos < UC) ? ulist[pos] : -1;
    int ra = (t >= 0) ? rankF[t] : KSEL;
    int rb = (t >= 0) ? rankL[t] : KSEL;
    int vA = (ra < KSEL) ? 1 : 0;
    int vB = (rb < KSEL) ? 1 : 0;
    int sA = vA ? sortedL[ra] : 0;
    int sB = vB ? sortedF[rb] : 0;
    srcAB[tid * 2] = sA;
    srcAB[tid * 2 + 1] = sB;
    tgl[tid] = t;
    fl[tid] = vA | (vB << 1);
    int cA = cid[sA], cB = cid[sB];
    mtA[tid] = cA;
    mtB[tid] = cB;
    float ab0 = attb[0];
    float sAv = aDot[sA] + gdot[cA] + ab0;
    float mxA = fmaxf(sAv, 0.f);
    float eA = expf(sAv - mxA), oA = expf(-mxA);
    float dA = eA + 255.f * oA;
    pqA[tid * 2] = eA / dA;
    pqA[tid * 2 + 1] = oA / dA;
    float sBv = aDot[sB] + gdot[cB] + ab0;
    float mxB = fmaxf(sBv, 0.f);
    float eB = expf(sBv - mxB), oB = expf(-mxB);
    float dB = eB + 255.f * oB;
    pqB[tid * 2] = eB / dB;
    pqB[tid * 2 + 1] = oB / dB;
  }
  __syncthreads();
  // stage both source tiles as bf16 (swizzled, same layout as before)
#pragma unroll
  for (int k = 0; k < 8; ++k) {
    int i = k * 256 + tid;
    int r = i >> 5, c4 = i & 31;
    int u2 = r * 32 + (c4 ^ ((r & 7) << 1));
    int wsA = srcAB[r * 2];
    float4 v = ((const float4*)(x + (size_t)wsA * D))[c4];
    uint2 pk;
    pk.x = (unsigned)f2bf(v.x) | ((unsigned)f2bf(v.y) << 16);
    pk.y = (unsigned)f2bf(v.z) | ((unsigned)f2bf(v.w) << 16);
    ((uint2*)xwA)[u2] = pk;
    int wsB = srcAB[r * 2 + 1];
    float4 u = ((const float4*)(x + (size_t)wsB * D))[c4];
    uint2 pk2;
    pk2.x = (unsigned)f2bf(u.x) | ((unsigned)f2bf(u.y) << 16);
    pk2.y = (unsigned)f2bf(u.z) | ((unsigned)f2bf(u.w) << 16);
    ((uint2*)xwB)[u2] = pk2;
  }
  __syncthreads();

  int w = tid >> 6;        // wave 0..3 -> rows w*16 .. w*16+15
  int l = tid & 63;
  int nl = l & 15;
  int khalf = l >> 4;
  int row = w * 16 + nl;

  f32x4 accA[8] = {};
  f32x4 accB[8] = {};
  const char* xbA = (const char*)xwA + row * 256;
  const char* xbB = (const char*)xwB + row * 256;
  unsigned rsw = (unsigned)((row & 7) << 4);
  bf16x8 bfrA[4], bfrB[4];
#pragma unroll
  for (int ks = 0; ks < 4; ++ks) {
    unsigned off = ((unsigned)(ks * 64 + khalf * 16)) ^ rsw;
    bfrA[ks] = *(const bf16x8*)(xbA + off);
    bfrB[ks] = *(const bf16x8*)(xbB + off);
  }
#pragma unroll
  for (int ks = 0; ks < 4; ++ks) {
#pragma unroll
    for (int ot = 0; ot < 8; ++ot) {
      bf16x8 afrag = *(const bf16x8*)(twT + (size_t)(ot * 16 + nl) * D + ks * 32 + khalf * 8);
      accA[ot] = __builtin_amdgcn_mfma_f32_16x16x32_bf16(afrag, bfrA[ks], accA[ot], 0, 0, 0);
      accB[ot] = __builtin_amdgcn_mfma_f32_16x16x32_bf16(afrag, bfrB[ks], accB[ot], 0, 0, 0);
    }
  }

  int t = tgl[row];
  int f = fl[row];
  float pA = pqA[row * 2], qA = pqA[row * 2 + 1];
  float pB = pqB[row * 2], qB = pqB[row * 2 + 1];
  int cA = mtA[row], cB = mtB[row];
#pragma unroll
  for (int ot = 0; ot < 8; ++ot) {
    int ch = ot * 16 + khalf * 4;
    float4 tbv = *(const float4*)(tb + ch);
    float4 swv = *(const float4*)(SW + ch);
    float4 hwA = *(const float4*)(HW + (size_t)cA * D + ch);
    float4 hwB = *(const float4*)(HW + (size_t)cB * D + ch);
    float4 oA, oB, o;
    oA.x = fmaxf(accA[ot][0] + tbv.x + qA * swv.x + (pA - qA) * hwA.x, 0.f);
    oA.y = fmaxf(accA[ot][1] + tbv.y + qA * swv.y + (pA - qA) * hwA.y, 0.f);
    oA.z = fmaxf(accA[ot][2] + tbv.z + qA * swv.z + (pA - qA) * hwA.z, 0.f);
    oA.w = fmaxf(accA[ot][3] + tbv.w + qA * swv.w + (pA - qA) * hwA.w, 0.f);
    oB.x = fmaxf(accB[ot][0] + tbv.x + qB * swv.x + (pB - qB) * hwB.x, 0.f);
    oB.y = fmaxf(accB[ot][1] + tbv.y + qB * swv.y + (pB - qB) * hwB.y, 0.f);
    oB.z = fmaxf(accB[ot][2] + tbv.z + qB * swv.z + (pB - qB) * hwB.z, 0.f);
    oB.w = fmaxf(accB[ot][3] + tbv.w + qB * swv.w + (pB - qB) * hwB.w, 0.f);
    if (f == 3) {
      o.x = (oA.x + oB.x) * 0.5f;
      o.y = (oA.y + oB.y) * 0.5f;
      o.z = (oA.z + oB.z) * 0.5f;
      o.w = (oA.w + oB.w) * 0.5f;
    } else if (f & 1) {
      o = oA;
    } else {
      o = oB;
    }
    if (t >= 0) *(float4*)(Fp + (size_t)t * D + ch) = o;
  }
}

// ======================= launcher =======================
extern "C" void kernel_launch(void* const* d_in, const int* in_sizes, int n_in,
                              void* d_out, int out_size, void* d_ws, size_t ws_size,
                              hipStream_t stream) {
  const float* x   = (const float*)d_in[0];
  const int* ei    = (const int*)d_in[1];
  const int* batch = (const int*)d_in[2];
  const int* cid   = (const int*)d_in[3];
  const float* w1  = (const float*)d_in[4];
  const float* b1  = (const float*)d_in[5];
  const float* w2  = (const float*)d_in[6];
  const float* b2  = (const float*)d_in[7];
  const float* gw  = (const float*)d_in[8];
  const float* gas = (const float*)d_in[9];
  const float* gad = (const float*)d_in[10];
  const float* gb  = (const float*)d_in[11];
  const float* wa  = (const float*)d_in[12];
  const float* wb  = (const float*)d_in[13];
  const float* ab  = (const float*)d_in[14];
  const float* tw  = (const float*)d_in[15];
  const float* tb  = (const float*)d_in[16];
  (void)in_sizes; (void)n_in; (void)ws_size; (void)out_size;

  char* p = (char*)d_ws;
  auto alloc = [&](size_t bytes) -> char* {
    char* r = p;
    p += (bytes + 255) & ~(size_t)255;
    return r;
  };
  // ---- zero-init region ----
  int* ccount    = (int*)alloc(C_ * 4);
  int* ccur      = (int*)alloc(C_ * 4);
  unsigned* mm   = (unsigned*)alloc(16);                // [maxF,maxL,minF,minL]
  int* hist2     = (int*)alloc(2 * NB * 4);
  int* cur2      = (int*)alloc(2 * NB * 4);
  float* Hc      = (float*)alloc((size_t)C_ * D * 4);   // atomic accumulator
  int* gcnt      = (int*)alloc(NBK * 4);
  size_t zeroBytes = (size_t)(p - (char*)d_ws);
  // ---- rest (fully written before read) ----
  int* cstart   = (int*)alloc(C_ * 4);
  int* cslot    = (int*)alloc((size_t)N * 4);
  float* gdot   = (float*)alloc(C_ * 4);
  float* SW     = (float*)alloc(D * 4);
  float* HW     = (float*)alloc((size_t)C_ * D * 4);
  unsigned short* twT = (unsigned short*)alloc((size_t)D * D * 2);
  float* score2 = (float*)alloc((size_t)2 * N * 4);     // [scoreF | scoreL]
  float* hg     = (float*)alloc((size_t)N * 4);
  float* aDot   = (float*)alloc((size_t)N * 4);
  unsigned* payload = (unsigned*)alloc((size_t)NBK * BCAP * 4);
  uint2* pmmF   = (uint2*)alloc((size_t)NSC64 * 8);
  uint2* pmmL   = (uint2*)alloc((size_t)NBK * 8);
  int* bucket2  = (int*)alloc((size_t)2 * N * 4);
  int* start2   = (int*)alloc(2 * NB * 4);
  int* slot2    = (int*)alloc((size_t)2 * N * 4);
  int* sorted2  = (int*)alloc((size_t)2 * N * 4);
  int* rank2    = (int*)alloc((size_t)2 * N * 4);
  int* csums    = (int*)alloc(NCHUNK * 4);
  int* cstarts  = (int*)alloc(NCHUNK * 4);
  int* mapping  = (int*)alloc((size_t)N * 4);
  int* ulist    = (int*)alloc((size_t)N * 4);

  float* scoreF = score2;
  float* scoreL = score2 + N;
  int* sortedF  = sorted2;
  int* sortedL  = sorted2 + N;
  int* rankF    = rank2;
  int* rankL    = rank2 + N;

  float* outF = (float*)d_out;             // [N, D]
  float* outE = outF + (size_t)N * D;      // [2, E]  (fully written by k_edge_zero)
  float* outB = outE + (size_t)2 * E_;     // [N]     (fully written by k_union_map)

  hipMemsetAsync(d_ws, 0, zeroBytes, stream);
  // outF: union rows fully written by k_fuseU; non-union rows zeroed by
  // k_edge_zero -> no 51 MB memset.

  // cluster means + derived (+ twT transpose folded into k_S_SW_HW grid)
  k_hist_cluster<<<(N + 255) / 256, 256, 0, stream>>>(cid, ccount);
  k_scan_small<<<1, 1024, 0, stream>>>(ccount, cstart, C_);
  k_scatter_cluster<<<(N + 255) / 256, 256, 0, stream>>>(cid, cstart, ccur, cslot);
  k_cluster_partial<<<C_ * CSEG, 128, 0, stream>>>(x, cstart, ccount, cslot, Hc);
  k_mean_gdot<<<C_, 128, 0, stream>>>(ccount, wb, Hc, gdot);
  k_S_SW_HW<<<C_ + 1 + D, 128, 0, stream>>>(Hc, tw, SW, HW, twT);

  // fused per-node scores (MLP + GAT projections + minmax partials) + edge softmax
  k_score64<<<NSC64, 256, 0, stream>>>(x, w1, b1, w2, b2, gw, wa, scoreF, hg, aDot, pmmF);
  k_escatter<<<(E_ + 8191) / 8192, 1024, 0, stream>>>(ei, gcnt, payload);
  k_esoftmax<<<NBK, 256, 0, stream>>>(payload, gcnt, hg, gas, gad, gb, scoreL, pmmL);
  k_mm_reduce<<<1, 1024, 0, stream>>>(pmmF, pmmL, mm);

  // exact ranking, both views per launch (minmax folded into producers + 1-block reduce)
  dim3 g2((N + 255) / 256, 2);
  k_bucket_hist2<<<g2, 256, 0, stream>>>(score2, mm, bucket2, hist2);
  k_scan_small<<<2, 1024, 0, stream>>>(hist2, start2, NB);
  k_bucket_scatter2<<<g2, 256, 0, stream>>>(bucket2, start2, cur2, slot2);
  dim3 gr(NB, 2);
  k_bucket_rank3<<<gr, 64, 0, stream>>>(score2, start2, hist2, slot2, rank2, sorted2);

  // union mapping (+ulist) + edge remap + batch + zero non-union rows (merged)
  k_union_chunksum<<<NCHUNK, 1024, 0, stream>>>(rankF, rankL, csums);
  k_scan_small<<<1, 1024, 0, stream>>>(csums, cstarts, NCHUNK);
  k_union_map<<<NCHUNK, 1024, 0, stream>>>(rankF, rankL, cstarts, batch, mapping, outB, ulist);
  k_edge_zero<<<EB + ZB, 256, 0, stream>>>(ei, mapping, outE, outF);

  // fused features: single target-centric launch over the union list
  k_fuseU<<<NSC64, 256, 0, stream>>>(x, twT, tb, SW, HW, gdot, aDot, cid,
                                     sortedF, sortedL, rankF, rankL, ulist,
                                     cstarts, csums, ab, outF);
}